// Round 2
// baseline (320.268 us; speedup 1.0000x reference)
//
#include <hip/hip_runtime.h>
#include <hip/hip_bf16.h>

#define BQ 8      // batches
#define NN 2048   // train rows (keys)
#define MM 1024   // test rows (queries)
#define EE 512    // input size
#define NH 6      // heads
#define AA 384    // attn size (NH*64)
#define CC 512    // classes

typedef __bf16 bf16x8 __attribute__((ext_vector_type(8)));
typedef float  f32x4  __attribute__((ext_vector_type(4)));
using bf16 = __hip_bfloat16;

static __device__ __forceinline__ f32x4 mfma16(bf16x8 a, bf16x8 b, f32x4 c) {
  return __builtin_amdgcn_mfma_f32_16x16x32_bf16(a, b, c, 0, 0, 0);
}

// ---------------- W[K][N] -> WT[N][K] bf16 ----------------
__global__ void transw_kernel(const float* __restrict__ W, bf16* __restrict__ WT) {
  int i = blockIdx.x * blockDim.x + threadIdx.x;
  if (i < EE * AA) {
    int k = i / AA, n = i - k * AA;
    WT[n * EE + k] = __float2bfloat16(W[i]);
  }
}

// ---------------- CSR build: per-batch class histogram + prefix + placement ----------------
__global__ __launch_bounds__(512) void build_kernel(const int* __restrict__ targets,
                                                    int* __restrict__ offs, int* __restrict__ idxs) {
  __shared__ int cnt[CC], ssum[CC], pos[CC];
  int b = blockIdx.x, tid = threadIdx.x;
  cnt[tid] = 0;
  __syncthreads();
  int t[4];
  #pragma unroll
  for (int i = 0; i < 4; i++) {
    t[i] = targets[b * NN + tid * 4 + i];
    atomicAdd(&cnt[t[i]], 1);
  }
  __syncthreads();
  ssum[tid] = cnt[tid];
  __syncthreads();
  for (int d = 1; d < CC; d <<= 1) {
    int v = (tid >= d) ? ssum[tid - d] : 0;
    __syncthreads();
    ssum[tid] += v;
    __syncthreads();
  }
  int excl = ssum[tid] - cnt[tid];
  offs[b * (CC + 1) + tid] = excl;
  if (tid == CC - 1) offs[b * (CC + 1) + CC] = NN;
  pos[tid] = excl;
  __syncthreads();
  #pragma unroll
  for (int i = 0; i < 4; i++) {
    int p = atomicAdd(&pos[t[i]], 1);
    idxs[b * NN + p] = tid * 4 + i;
  }
}

// ---------------- projections (f32 in, bf16 out): 3072 independent wave-units ----------------
__global__ __launch_bounds__(256, 3) void proj_kernel(
    const float* __restrict__ test, const float* __restrict__ train,
    const bf16* __restrict__ WqT, const bf16* __restrict__ WkT,
    const float* __restrict__ bq, const float* __restrict__ bk,
    bf16* __restrict__ Qb, bf16* __restrict__ Kb)
{
  int wid = threadIdx.x >> 6, lane = threadIdx.x & 63;
  int unit = blockIdx.x * 4 + wid;       // 3072 units = (512 Q + 1024 K) m-units x 2 nt-halves
  int sub = unit & 1, mu = unit >> 1;
  const float* A; const bf16* WT; const float* bias; bf16* C; float scale; int m0;
  if (mu < 512) { A = test;  WT = WqT; bias = bq; C = Qb; scale = 0.125f; m0 = mu * 16; }
  else          { A = train; WT = WkT; bias = bk; C = Kb; scale = 1.0f;   m0 = (mu - 512) * 16; }
  int row = lane & 15, hi = lane >> 4;

  bf16x8 af[16];
  const float* arow = A + (size_t)(m0 + row) * EE + hi * 8;
  #pragma unroll
  for (int ks = 0; ks < 16; ks++) {
    bf16x8 v;
    #pragma unroll
    for (int j = 0; j < 8; j++) v[j] = (__bf16)arow[ks * 32 + j];
    af[ks] = v;
  }

  int nt0 = sub * 12;
  #pragma unroll 1
  for (int nt = nt0; nt < nt0 + 12; nt++) {
    const bf16* wrow = WT + (size_t)(nt * 16 + row) * EE + hi * 8;
    f32x4 acc0 = {0.f, 0.f, 0.f, 0.f}, acc1 = {0.f, 0.f, 0.f, 0.f};
    #pragma unroll
    for (int ks = 0; ks < 16; ks += 2) {
      acc0 = mfma16(af[ks],     *reinterpret_cast<const bf16x8*>(wrow + ks * 32), acc0);
      acc1 = mfma16(af[ks + 1], *reinterpret_cast<const bf16x8*>(wrow + (ks + 1) * 32), acc1);
    }
    f32x4 acc = acc0 + acc1;
    int ocol = nt * 16 + row;
    float bv = bias[ocol];
    #pragma unroll
    for (int j = 0; j < 4; j++)
      C[(size_t)(m0 + hi * 4 + j) * AA + ocol] = __float2bfloat16((acc[j] + bv) * scale);
  }
}

// ---------------- pass 1: Z partials. grid = 8b x 16mt(64m) x 8nc(256n) = 1024 ----------------
__global__ __launch_bounds__(256, 4) void zpass_kernel(
    const bf16* __restrict__ Qb, const bf16* __restrict__ Kb, float* __restrict__ Zp)
{
  int id = blockIdx.x;
  int b = id & 7, r = id >> 3, mt = r & 15, nc = r >> 4;
  int wid = threadIdx.x >> 6, lane = threadIdx.x & 63;
  int m0 = mt * 64 + wid * 16, n0 = nc * 256;
  int row = lane & 15, hi = lane >> 4;

  bf16x8 qf[12];
  const bf16* qrow = Qb + ((size_t)(b * MM + m0 + row)) * AA + hi * 8;
  #pragma unroll
  for (int ks = 0; ks < 12; ks++) qf[ks] = *reinterpret_cast<const bf16x8*>(qrow + ks * 32);

  float zacc[NH][4];
  #pragma unroll
  for (int h = 0; h < NH; h++)
    #pragma unroll
    for (int j = 0; j < 4; j++) zacc[h][j] = 0.f;

  const bf16* kbase = Kb + ((size_t)(b * NN + n0 + row)) * AA + hi * 8;
  #pragma unroll 1
  for (int nt = 0; nt < 16; nt++) {
    const bf16* krow = kbase + (size_t)nt * 16 * AA;
    #pragma unroll
    for (int h = 0; h < NH; h++) {
      f32x4 acc = {0.f, 0.f, 0.f, 0.f};
      acc = mfma16(qf[2 * h],     *reinterpret_cast<const bf16x8*>(krow + (2 * h) * 32), acc);
      acc = mfma16(qf[2 * h + 1], *reinterpret_cast<const bf16x8*>(krow + (2 * h + 1) * 32), acc);
      #pragma unroll
      for (int j = 0; j < 4; j++) zacc[h][j] += __expf(acc[j]);
    }
  }
  #pragma unroll
  for (int h = 0; h < NH; h++)
    #pragma unroll
    for (int j = 0; j < 4; j++) {
      float v = zacc[h][j];
      v += __shfl_xor(v, 1); v += __shfl_xor(v, 2);
      v += __shfl_xor(v, 4); v += __shfl_xor(v, 8);
      zacc[h][j] = v;
    }
  if (row == 0) {
    #pragma unroll
    for (int h = 0; h < NH; h++)
      #pragma unroll
      for (int j = 0; j < 4; j++)
        Zp[(((size_t)nc * 8 + b) * NH + h) * MM + m0 + hi * 4 + j] = zacc[h][j];
  }
}

// ---------------- pass 2: normalized head-combined weights W[b][m][n] bf16 ----------------
__global__ __launch_bounds__(256, 3) void wpass_kernel(
    const bf16* __restrict__ Qb, const bf16* __restrict__ Kb,
    const float* __restrict__ Zp, bf16* __restrict__ W)
{
  int id = blockIdx.x;
  int b = id & 7, r = id >> 3, mt = r & 15, nc = r >> 4;
  int wid = threadIdx.x >> 6, lane = threadIdx.x & 63;
  int m0 = mt * 64 + wid * 16, n0 = nc * 256;
  int row = lane & 15, hi = lane >> 4;

  bf16x8 qf[12];
  const bf16* qrow = Qb + ((size_t)(b * MM + m0 + row)) * AA + hi * 8;
  #pragma unroll
  for (int ks = 0; ks < 12; ks++) qf[ks] = *reinterpret_cast<const bf16x8*>(qrow + ks * 32);

  float rz[NH][4];
  #pragma unroll
  for (int h = 0; h < NH; h++)
    #pragma unroll
    for (int j = 0; j < 4; j++) {
      int m = m0 + hi * 4 + j;
      float z = 0.f;
      #pragma unroll
      for (int p = 0; p < 8; p++) z += Zp[(((size_t)p * 8 + b) * NH + h) * MM + m];
      rz[h][j] = 1.0f / (6.0f * z);     // fold mean-over-heads here
    }

  const bf16* kbase = Kb + ((size_t)(b * NN + n0 + row)) * AA + hi * 8;
  #pragma unroll 1
  for (int nt = 0; nt < 16; nt++) {
    const bf16* krow = kbase + (size_t)nt * 16 * AA;
    float w0 = 0.f, w1 = 0.f, w2 = 0.f, w3 = 0.f;
    #pragma unroll
    for (int h = 0; h < NH; h++) {
      f32x4 acc = {0.f, 0.f, 0.f, 0.f};
      acc = mfma16(qf[2 * h],     *reinterpret_cast<const bf16x8*>(krow + (2 * h) * 32), acc);
      acc = mfma16(qf[2 * h + 1], *reinterpret_cast<const bf16x8*>(krow + (2 * h + 1) * 32), acc);
      w0 += __expf(acc[0]) * rz[h][0];
      w1 += __expf(acc[1]) * rz[h][1];
      w2 += __expf(acc[2]) * rz[h][2];
      w3 += __expf(acc[3]) * rz[h][3];
    }
    int n = n0 + nt * 16 + row;
    size_t base = ((size_t)(b * MM + m0 + hi * 4)) * NN + n;
    W[base]          = __float2bfloat16(w0);
    W[base + NN]     = __float2bfloat16(w1);
    W[base + 2 * NN] = __float2bfloat16(w2);
    W[base + 3 * NN] = __float2bfloat16(w3);
  }
}

// ---------------- pass 3: CSR gather + log. grid = 8b x 64 m-chunks(16m) = 512 ----------------
__global__ __launch_bounds__(512) void gather_kernel(
    const bf16* __restrict__ W, const int* __restrict__ offs,
    const int* __restrict__ idxs, float* __restrict__ out)
{
  __shared__ bf16 wl[16 * NN];          // 64 KB
  int id = blockIdx.x;
  int b = id & 7, mt = id >> 3;
  int m0 = mt * 16;
  int tid = threadIdx.x;

  const uint4* src = (const uint4*)(W + ((size_t)(b * MM + m0)) * NN);
  uint4* dst = (uint4*)wl;
  #pragma unroll
  for (int i = tid; i < 16 * NN / 8; i += 512) dst[i] = src[i];
  __syncthreads();

  int c = tid;
  int o0 = offs[b * (CC + 1) + c], o1 = offs[b * (CC + 1) + c + 1];
  const int* il = idxs + b * NN;
  #pragma unroll 1
  for (int mi = 0; mi < 16; mi++) {
    float s = 0.f;
    for (int i = o0; i < o1; i++) s += __bfloat162float(wl[mi * NN + il[i]]);
    out[((size_t)(m0 + mi) * BQ + b) * CC + c] = __logf(fmaxf(s, 1e-5f) + 3e-5f);
  }
}

extern "C" void kernel_launch(void* const* d_in, const int* in_sizes, int n_in,
                              void* d_out, int out_size, void* d_ws, size_t ws_size,
                              hipStream_t stream) {
  const float* train = (const float*)d_in[0];
  const float* test  = (const float*)d_in[1];
  const int*   tgt   = (const int*)d_in[2];
  const float* Wq    = (const float*)d_in[3];
  const float* bq    = (const float*)d_in[4];
  const float* Wk    = (const float*)d_in[5];
  const float* bk    = (const float*)d_in[6];
  float* out = (float*)d_out;

  char* ws = (char*)d_ws;
  bf16*  WqT  = (bf16*)(ws);                       //    393,216 B
  bf16*  WkT  = (bf16*)(ws + 393216);              //    393,216 B
  bf16*  Qb   = (bf16*)(ws + 786432);              //  6,291,456 B
  bf16*  Kb   = (bf16*)(ws + 7077888);             // 12,582,912 B
  float* Zp   = (float*)(ws + 19660800);           //  1,572,864 B
  bf16*  Wbuf = (bf16*)(ws + 21233664);            // 33,554,432 B
  int*   offs = (int*)(ws + 54788096);             //     16,416 B
  int*   idxs = (int*)(ws + 54804512);             //     65,536 B  (total ~54.9 MB)

  transw_kernel<<<(EE * AA + 255) / 256, 256, 0, stream>>>(Wq, WqT);
  transw_kernel<<<(EE * AA + 255) / 256, 256, 0, stream>>>(Wk, WkT);
  build_kernel<<<BQ, 512, 0, stream>>>(tgt, offs, idxs);
  proj_kernel<<<768, 256, 0, stream>>>(test, train, WqT, WkT, bq, bk, Qb, Kb);
  zpass_kernel<<<1024, 256, 0, stream>>>(Qb, Kb, Zp);
  wpass_kernel<<<1024, 256, 0, stream>>>(Qb, Kb, Zp, Wbuf);
  gather_kernel<<<512, 512, 0, stream>>>(Wbuf, offs, idxs, out);
}

// Round 3
// 198.205 us; speedup vs baseline: 1.6158x; 1.6158x over previous
//
#include <hip/hip_runtime.h>
#include <hip/hip_bf16.h>

#define BQ 8      // batches
#define NN 2048   // train rows (keys)
#define MM 1024   // test rows (queries)
#define EE 512    // input size
#define NH 6      // heads
#define AA 384    // attn size (NH*64)
#define CC 512    // classes

#define KROW_B (AA * 2)          // 768 bytes per K row
#define TILE_B (16 * KROW_B)     // 12288 bytes per 16-row K tile

typedef __bf16 bf16x8 __attribute__((ext_vector_type(8)));
typedef float  f32x4  __attribute__((ext_vector_type(4)));
using bf16 = __hip_bfloat16;

static __device__ __forceinline__ f32x4 mfma16(bf16x8 a, bf16x8 b, f32x4 c) {
  return __builtin_amdgcn_mfma_f32_16x16x32_bf16(a, b, c, 0, 0, 0);
}

typedef __attribute__((address_space(1))) const void gconst_void;
typedef __attribute__((address_space(3))) void lds_void_t;
static __device__ __forceinline__ void ld_lds16(const void* g, void* l) {
  __builtin_amdgcn_global_load_lds((gconst_void*)g, (lds_void_t*)l, 16, 0, 0);
}

// ---------------- W[K][N] -> WT[N][K] bf16 ----------------
__global__ void transw_kernel(const float* __restrict__ W, bf16* __restrict__ WT) {
  int i = blockIdx.x * blockDim.x + threadIdx.x;
  if (i < EE * AA) {
    int k = i / AA, n = i - k * AA;
    WT[n * EE + k] = __float2bfloat16(W[i]);
  }
}

// ---------------- CSR build ----------------
__global__ __launch_bounds__(512) void build_kernel(const int* __restrict__ targets,
                                                    int* __restrict__ offs, int* __restrict__ idxs) {
  __shared__ int cnt[CC], ssum[CC], pos[CC];
  int b = blockIdx.x, tid = threadIdx.x;
  cnt[tid] = 0;
  __syncthreads();
  int t[4];
  #pragma unroll
  for (int i = 0; i < 4; i++) {
    t[i] = targets[b * NN + tid * 4 + i];
    atomicAdd(&cnt[t[i]], 1);
  }
  __syncthreads();
  ssum[tid] = cnt[tid];
  __syncthreads();
  for (int d = 1; d < CC; d <<= 1) {
    int v = (tid >= d) ? ssum[tid - d] : 0;
    __syncthreads();
    ssum[tid] += v;
    __syncthreads();
  }
  int excl = ssum[tid] - cnt[tid];
  offs[b * (CC + 1) + tid] = excl;
  if (tid == CC - 1) offs[b * (CC + 1) + CC] = NN;
  pos[tid] = excl;
  __syncthreads();
  #pragma unroll
  for (int i = 0; i < 4; i++) {
    int p = atomicAdd(&pos[t[i]], 1);
    idxs[b * NN + p] = tid * 4 + i;
  }
}

// ---------------- projections (f32 in, bf16 out) ----------------
__global__ __launch_bounds__(256, 3) void proj_kernel(
    const float* __restrict__ test, const float* __restrict__ train,
    const bf16* __restrict__ WqT, const bf16* __restrict__ WkT,
    const float* __restrict__ bq, const float* __restrict__ bk,
    bf16* __restrict__ Qb, bf16* __restrict__ Kb)
{
  int wid = threadIdx.x >> 6, lane = threadIdx.x & 63;
  int unit = blockIdx.x * 4 + wid;
  int sub = unit & 1, mu = unit >> 1;
  const float* A; const bf16* WT; const float* bias; bf16* C; float scale; int m0;
  if (mu < 512) { A = test;  WT = WqT; bias = bq; C = Qb; scale = 0.125f; m0 = mu * 16; }
  else          { A = train; WT = WkT; bias = bk; C = Kb; scale = 1.0f;   m0 = (mu - 512) * 16; }
  int row = lane & 15, hi = lane >> 4;

  bf16x8 af[16];
  const float* arow = A + (size_t)(m0 + row) * EE + hi * 8;
  #pragma unroll
  for (int ks = 0; ks < 16; ks++) {
    bf16x8 v;
    #pragma unroll
    for (int j = 0; j < 8; j++) v[j] = (__bf16)arow[ks * 32 + j];
    af[ks] = v;
  }

  int nt0 = sub * 12;
  #pragma unroll 1
  for (int nt = nt0; nt < nt0 + 12; nt++) {
    const bf16* wrow = WT + (size_t)(nt * 16 + row) * EE + hi * 8;
    f32x4 acc0 = {0.f, 0.f, 0.f, 0.f}, acc1 = {0.f, 0.f, 0.f, 0.f};
    #pragma unroll
    for (int ks = 0; ks < 16; ks += 2) {
      acc0 = mfma16(af[ks],     *reinterpret_cast<const bf16x8*>(wrow + ks * 32), acc0);
      acc1 = mfma16(af[ks + 1], *reinterpret_cast<const bf16x8*>(wrow + (ks + 1) * 32), acc1);
    }
    f32x4 acc = acc0 + acc1;
    int ocol = nt * 16 + row;
    float bv = bias[ocol];
    #pragma unroll
    for (int j = 0; j < 4; j++)
      C[(size_t)(m0 + hi * 4 + j) * AA + ocol] = __float2bfloat16((acc[j] + bv) * scale);
  }
}

// ================= shared staging helpers for score passes =================
// LDS tile: 16 K-rows x 768B, XOR-swizzled: LDS[row][c ^ ((row&7)<<4)] = K[row][c].
// Staged via global_load_lds (linear LDS dest, inverse-swizzled global source).

// ---------------- pass 1: Z partials. grid = 8b x 16mt(64m) x 8nc(256n) = 1024 ----------------
__global__ __launch_bounds__(256) void zpass_kernel(
    const bf16* __restrict__ Qb, const bf16* __restrict__ Kb, float* __restrict__ Zp)
{
  __shared__ char kbuf[2][TILE_B];
  int id = blockIdx.x;
  int b = id & 7, r = id >> 3, mt = r & 15, nc = r >> 4;
  int tid = threadIdx.x, wid = tid >> 6, lane = tid & 63;
  int m0 = mt * 64 + wid * 16, n0 = nc * 256;
  int row = lane & 15, hi = lane >> 4;

  bf16x8 qf[12];
  const bf16* qrow = Qb + ((size_t)(b * MM + m0 + row)) * AA + hi * 8;
  #pragma unroll
  for (int ks = 0; ks < 12; ks++) qf[ks] = *reinterpret_cast<const bf16x8*>(qrow + ks * 32);

  // staging offsets (3 x 16B per thread)
  int ldso[3], srco[3];
  #pragma unroll
  for (int i = 0; i < 3; i++) {
    int off = wid * 3072 + i * 1024 + lane * 16;
    int rw = off / KROW_B, c = off - rw * KROW_B;
    ldso[i] = off;
    srco[i] = rw * KROW_B + (c ^ ((rw & 7) << 4));
  }
  const char* kgbase = (const char*)(Kb + ((size_t)(b * NN + n0)) * AA);

  // read-side swizzle precompute
  int sw = (row & 7) << 4;
  int rbase = row * KROW_B;
  int x0 = rbase + ((hi * 16) ^ sw);
  int x1 = rbase + (((hi * 16) + 64) ^ sw);

  float zacc[NH][4];
  #pragma unroll
  for (int h = 0; h < NH; h++)
    #pragma unroll
    for (int j = 0; j < 4; j++) zacc[h][j] = 0.f;

  // prologue: stage tile 0
  #pragma unroll
  for (int i = 0; i < 3; i++) ld_lds16(kgbase + srco[i], kbuf[0] + ldso[i]);
  __syncthreads();

  #pragma unroll 1
  for (int nt = 0; nt < 16; nt++) {
    int cur = nt & 1;
    if (nt < 15) {
      const char* src = kgbase + (size_t)(nt + 1) * TILE_B;
      #pragma unroll
      for (int i = 0; i < 3; i++) ld_lds16(src + srco[i], kbuf[cur ^ 1] + ldso[i]);
    }
    const char* kb = kbuf[cur];
    #pragma unroll
    for (int h = 0; h < NH; h++) {
      bf16x8 k0 = *reinterpret_cast<const bf16x8*>(kb + h * 128 + x0);
      bf16x8 k1 = *reinterpret_cast<const bf16x8*>(kb + h * 128 + x1);
      f32x4 acc = {0.f, 0.f, 0.f, 0.f};
      acc = mfma16(qf[2 * h], k0, acc);
      acc = mfma16(qf[2 * h + 1], k1, acc);
      #pragma unroll
      for (int j = 0; j < 4; j++) zacc[h][j] += __expf(acc[j]);
    }
    __syncthreads();
  }

  #pragma unroll
  for (int h = 0; h < NH; h++)
    #pragma unroll
    for (int j = 0; j < 4; j++) {
      float v = zacc[h][j];
      v += __shfl_xor(v, 1); v += __shfl_xor(v, 2);
      v += __shfl_xor(v, 4); v += __shfl_xor(v, 8);
      zacc[h][j] = v;
    }
  if (row == 0) {
    #pragma unroll
    for (int h = 0; h < NH; h++)
      #pragma unroll
      for (int j = 0; j < 4; j++)
        Zp[(((size_t)nc * 8 + b) * NH + h) * MM + m0 + hi * 4 + j] = zacc[h][j];
  }
}

// ---------------- pass 2: normalized head-combined weights W[b][m][n] bf16 ----------------
__global__ __launch_bounds__(256) void wpass_kernel(
    const bf16* __restrict__ Qb, const bf16* __restrict__ Kb,
    const float* __restrict__ Zp, bf16* __restrict__ W)
{
  __shared__ char kbuf[2][TILE_B];
  int id = blockIdx.x;
  int b = id & 7, r = id >> 3, mt = r & 15, nc = r >> 4;
  int tid = threadIdx.x, wid = tid >> 6, lane = tid & 63;
  int m0 = mt * 64 + wid * 16, n0 = nc * 256;
  int row = lane & 15, hi = lane >> 4;

  bf16x8 qf[12];
  const bf16* qrow = Qb + ((size_t)(b * MM + m0 + row)) * AA + hi * 8;
  #pragma unroll
  for (int ks = 0; ks < 12; ks++) qf[ks] = *reinterpret_cast<const bf16x8*>(qrow + ks * 32);

  float rz[NH][4];
  #pragma unroll
  for (int h = 0; h < NH; h++)
    #pragma unroll
    for (int j = 0; j < 4; j++) {
      int m = m0 + hi * 4 + j;
      float z = 0.f;
      #pragma unroll
      for (int p = 0; p < 8; p++) z += Zp[(((size_t)p * 8 + b) * NH + h) * MM + m];
      rz[h][j] = 1.0f / (6.0f * z);
    }

  int ldso[3], srco[3];
  #pragma unroll
  for (int i = 0; i < 3; i++) {
    int off = wid * 3072 + i * 1024 + lane * 16;
    int rw = off / KROW_B, c = off - rw * KROW_B;
    ldso[i] = off;
    srco[i] = rw * KROW_B + (c ^ ((rw & 7) << 4));
  }
  const char* kgbase = (const char*)(Kb + ((size_t)(b * NN + n0)) * AA);

  int sw = (row & 7) << 4;
  int rbase = row * KROW_B;
  int x0 = rbase + ((hi * 16) ^ sw);
  int x1 = rbase + (((hi * 16) + 64) ^ sw);

  #pragma unroll
  for (int i = 0; i < 3; i++) ld_lds16(kgbase + srco[i], kbuf[0] + ldso[i]);
  __syncthreads();

  #pragma unroll 1
  for (int nt = 0; nt < 16; nt++) {
    int cur = nt & 1;
    if (nt < 15) {
      const char* src = kgbase + (size_t)(nt + 1) * TILE_B;
      #pragma unroll
      for (int i = 0; i < 3; i++) ld_lds16(src + srco[i], kbuf[cur ^ 1] + ldso[i]);
    }
    const char* kb = kbuf[cur];
    float w0 = 0.f, w1 = 0.f, w2 = 0.f, w3 = 0.f;
    #pragma unroll
    for (int h = 0; h < NH; h++) {
      bf16x8 k0 = *reinterpret_cast<const bf16x8*>(kb + h * 128 + x0);
      bf16x8 k1 = *reinterpret_cast<const bf16x8*>(kb + h * 128 + x1);
      f32x4 acc = {0.f, 0.f, 0.f, 0.f};
      acc = mfma16(qf[2 * h], k0, acc);
      acc = mfma16(qf[2 * h + 1], k1, acc);
      w0 += __expf(acc[0]) * rz[h][0];
      w1 += __expf(acc[1]) * rz[h][1];
      w2 += __expf(acc[2]) * rz[h][2];
      w3 += __expf(acc[3]) * rz[h][3];
    }
    int n = n0 + nt * 16 + row;
    size_t base = ((size_t)(b * MM + m0 + hi * 4)) * NN + n;
    W[base]          = __float2bfloat16(w0);
    W[base + NN]     = __float2bfloat16(w1);
    W[base + 2 * NN] = __float2bfloat16(w2);
    W[base + 3 * NN] = __float2bfloat16(w3);
    __syncthreads();
  }
}

// ---------------- pass 3: CSR gather + log ----------------
__global__ __launch_bounds__(512) void gather_kernel(
    const bf16* __restrict__ W, const int* __restrict__ offs,
    const int* __restrict__ idxs, float* __restrict__ out)
{
  __shared__ bf16 wl[16 * NN];          // 64 KB
  int id = blockIdx.x;
  int b = id & 7, mt = id >> 3;
  int m0 = mt * 16;
  int tid = threadIdx.x;

  const uint4* src = (const uint4*)(W + ((size_t)(b * MM + m0)) * NN);
  uint4* dst = (uint4*)wl;
  #pragma unroll
  for (int i = tid; i < 16 * NN / 8; i += 512) dst[i] = src[i];
  __syncthreads();

  int c = tid;
  int o0 = offs[b * (CC + 1) + c], o1 = offs[b * (CC + 1) + c + 1];
  const int* il = idxs + b * NN;
  #pragma unroll 1
  for (int mi = 0; mi < 16; mi++) {
    float s = 0.f;
    for (int i = o0; i < o1; i++) s += __bfloat162float(wl[mi * NN + il[i]]);
    out[((size_t)(m0 + mi) * BQ + b) * CC + c] = __logf(fmaxf(s, 1e-5f) + 3e-5f);
  }
}

extern "C" void kernel_launch(void* const* d_in, const int* in_sizes, int n_in,
                              void* d_out, int out_size, void* d_ws, size_t ws_size,
                              hipStream_t stream) {
  const float* train = (const float*)d_in[0];
  const float* test  = (const float*)d_in[1];
  const int*   tgt   = (const int*)d_in[2];
  const float* Wq    = (const float*)d_in[3];
  const float* bq    = (const float*)d_in[4];
  const float* Wk    = (const float*)d_in[5];
  const float* bk    = (const float*)d_in[6];
  float* out = (float*)d_out;

  char* ws = (char*)d_ws;
  bf16*  WqT  = (bf16*)(ws);                       //    393,216 B
  bf16*  WkT  = (bf16*)(ws + 393216);              //    393,216 B
  bf16*  Qb   = (bf16*)(ws + 786432);              //  6,291,456 B
  bf16*  Kb   = (bf16*)(ws + 7077888);             // 12,582,912 B
  float* Zp   = (float*)(ws + 19660800);           //  1,572,864 B
  bf16*  Wbuf = (bf16*)(ws + 21233664);            // 33,554,432 B
  int*   offs = (int*)(ws + 54788096);             //     16,416 B
  int*   idxs = (int*)(ws + 54804512);             //     65,536 B

  transw_kernel<<<(EE * AA + 255) / 256, 256, 0, stream>>>(Wq, WqT);
  transw_kernel<<<(EE * AA + 255) / 256, 256, 0, stream>>>(Wk, WkT);
  build_kernel<<<BQ, 512, 0, stream>>>(tgt, offs, idxs);
  proj_kernel<<<768, 256, 0, stream>>>(test, train, WqT, WkT, bq, bk, Qb, Kb);
  zpass_kernel<<<1024, 256, 0, stream>>>(Qb, Kb, Zp);
  wpass_kernel<<<1024, 256, 0, stream>>>(Qb, Kb, Zp, Wbuf);
  gather_kernel<<<512, 512, 0, stream>>>(Wbuf, offs, idxs, out);
}

// Round 4
// 148.374 us; speedup vs baseline: 2.1585x; 1.3358x over previous
//
#include <hip/hip_runtime.h>
#include <hip/hip_bf16.h>

#define BQ 8      // batches
#define NN 2048   // train rows (keys)
#define MM 1024   // test rows (queries)
#define EE 512    // input size
#define NH 6      // heads
#define AA 384    // attn size (NH*64)
#define CC 512    // classes

#define KROW_B (AA * 2)          // 768 bytes per K row
#define TILE_B (16 * KROW_B)     // 12288 bytes per 16-row K tile
#define WROW_B (EE * 2)          // 1024 bytes per W row
#define WTILE_B (16 * WROW_B)    // 16384 bytes per 16-row W tile

typedef __bf16 bf16x8 __attribute__((ext_vector_type(8)));
typedef float  f32x4  __attribute__((ext_vector_type(4)));
using bf16 = __hip_bfloat16;

static __device__ __forceinline__ f32x4 mfma16(bf16x8 a, bf16x8 b, f32x4 c) {
  return __builtin_amdgcn_mfma_f32_16x16x32_bf16(a, b, c, 0, 0, 0);
}

typedef __attribute__((address_space(1))) const void gconst_void;
typedef __attribute__((address_space(3))) void lds_void_t;
static __device__ __forceinline__ void ld_lds16(const void* g, void* l) {
  __builtin_amdgcn_global_load_lds((gconst_void*)g, (lds_void_t*)l, 16, 0, 0);
}

// ---------------- W[K][N] -> WT[N][K] bf16 ----------------
__global__ void transw_kernel(const float* __restrict__ W, bf16* __restrict__ WT) {
  int i = blockIdx.x * blockDim.x + threadIdx.x;
  if (i < EE * AA) {
    int k = i / AA, n = i - k * AA;
    WT[n * EE + k] = __float2bfloat16(W[i]);
  }
}

// ---------------- CSR build ----------------
__global__ __launch_bounds__(512) void build_kernel(const int* __restrict__ targets,
                                                    int* __restrict__ offs, int* __restrict__ idxs) {
  __shared__ int cnt[CC], ssum[CC], pos[CC];
  int b = blockIdx.x, tid = threadIdx.x;
  cnt[tid] = 0;
  __syncthreads();
  int t[4];
  #pragma unroll
  for (int i = 0; i < 4; i++) {
    t[i] = targets[b * NN + tid * 4 + i];
    atomicAdd(&cnt[t[i]], 1);
  }
  __syncthreads();
  ssum[tid] = cnt[tid];
  __syncthreads();
  for (int d = 1; d < CC; d <<= 1) {
    int v = (tid >= d) ? ssum[tid - d] : 0;
    __syncthreads();
    ssum[tid] += v;
    __syncthreads();
  }
  int excl = ssum[tid] - cnt[tid];
  offs[b * (CC + 1) + tid] = excl;
  if (tid == CC - 1) offs[b * (CC + 1) + CC] = NN;
  pos[tid] = excl;
  __syncthreads();
  #pragma unroll
  for (int i = 0; i < 4; i++) {
    int p = atomicAdd(&pos[t[i]], 1);
    idxs[b * NN + p] = tid * 4 + i;
  }
}

// ---------------- projections (f32 in, bf16 out), LDS-staged W, 2-phase ----------------
// grid = 768: (128 Q-units + 256 K-units of 64 rows) x 2 n-halves
__global__ __launch_bounds__(256, 3) void proj_kernel(
    const float* __restrict__ test, const float* __restrict__ train,
    const bf16* __restrict__ WqT, const bf16* __restrict__ WkT,
    const float* __restrict__ bq, const float* __restrict__ bk,
    bf16* __restrict__ Qb, bf16* __restrict__ Kb)
{
  __shared__ char wbuf[2][WTILE_B];   // 32 KB
  int tid = threadIdx.x, wid = tid >> 6, lane = tid & 63;
  int bid = blockIdx.x;
  int sub = bid & 1, unit = bid >> 1;
  const float* A; const bf16* WT; const float* bias; bf16* C; float scale; int m0;
  if (unit < 128) { A = test;  WT = WqT; bias = bq; C = Qb; scale = 0.125f; m0 = unit * 64; }
  else            { A = train; WT = WkT; bias = bk; C = Kb; scale = 1.0f;   m0 = (unit - 128) * 64; }
  m0 += wid * 16;
  int row = lane & 15, hi = lane >> 4;

  // A fragments: f32 -> bf16, 16 rows x 512 k per wave (64 VGPR)
  bf16x8 af[16];
  const float* arow = A + (size_t)(m0 + row) * EE + hi * 8;
  #pragma unroll
  for (int ks = 0; ks < 16; ks++) {
    float4 u = *reinterpret_cast<const float4*>(arow + ks * 32);
    float4 v = *reinterpret_cast<const float4*>(arow + ks * 32 + 4);
    bf16x8 f;
    f[0] = (__bf16)u.x; f[1] = (__bf16)u.y; f[2] = (__bf16)u.z; f[3] = (__bf16)u.w;
    f[4] = (__bf16)v.x; f[5] = (__bf16)v.y; f[6] = (__bf16)v.z; f[7] = (__bf16)v.w;
    af[ks] = f;
  }

  // staging offsets: 4 x 16B per thread; linear LDS dest, inverse-swizzled source
  int ldso[4], srco[4];
  #pragma unroll
  for (int i = 0; i < 4; i++) {
    int off = tid * 16 + i * 4096;
    int rw = off >> 10, c = off & 1023;
    ldso[i] = off;
    srco[i] = rw * WROW_B + (c ^ ((rw & 7) << 4));
  }
  const char* wgbase = (const char*)WT + (size_t)sub * 12 * WTILE_B;
  int sw = (row & 7) << 4;

  // prologue: stage tile 0
  #pragma unroll
  for (int i = 0; i < 4; i++) ld_lds16(wgbase + srco[i], wbuf[0] + ldso[i]);
  __syncthreads();

  #pragma unroll 1
  for (int t = 0; t < 12; t++) {
    int cur = t & 1;
    if (t < 11) {
      const char* src = wgbase + (size_t)(t + 1) * WTILE_B;
      #pragma unroll
      for (int i = 0; i < 4; i++) ld_lds16(src + srco[i], wbuf[cur ^ 1] + ldso[i]);
    }
    const char* wb = wbuf[cur] + row * WROW_B;
    f32x4 acc0 = {0.f, 0.f, 0.f, 0.f}, acc1 = {0.f, 0.f, 0.f, 0.f};
    #pragma unroll
    for (int ks = 0; ks < 16; ks += 2) {
      bf16x8 w0 = *reinterpret_cast<const bf16x8*>(wb + ((hi * 16 + ks * 64) ^ sw));
      bf16x8 w1 = *reinterpret_cast<const bf16x8*>(wb + ((hi * 16 + (ks + 1) * 64) ^ sw));
      acc0 = mfma16(af[ks], w0, acc0);
      acc1 = mfma16(af[ks + 1], w1, acc1);
    }
    f32x4 acc = acc0 + acc1;
    int ocol = (sub * 12 + t) * 16 + row;
    float bv = bias[ocol];
    #pragma unroll
    for (int j = 0; j < 4; j++)
      C[(size_t)(m0 + hi * 4 + j) * AA + ocol] = __float2bfloat16((acc[j] + bv) * scale);
    __syncthreads();
  }
}

// ---------------- pass 1: Z partials. grid = 8b x 16mt(64m) x 8nc(256n) = 1024 ----------------
__global__ __launch_bounds__(256) void zpass_kernel(
    const bf16* __restrict__ Qb, const bf16* __restrict__ Kb, float* __restrict__ Zp)
{
  __shared__ char kbuf[2][TILE_B];
  int id = blockIdx.x;
  int b = id & 7, r = id >> 3, mt = r & 15, nc = r >> 4;
  int tid = threadIdx.x, wid = tid >> 6, lane = tid & 63;
  int m0 = mt * 64 + wid * 16, n0 = nc * 256;
  int row = lane & 15, hi = lane >> 4;

  bf16x8 qf[12];
  const bf16* qrow = Qb + ((size_t)(b * MM + m0 + row)) * AA + hi * 8;
  #pragma unroll
  for (int ks = 0; ks < 12; ks++) qf[ks] = *reinterpret_cast<const bf16x8*>(qrow + ks * 32);

  int ldso[3], srco[3];
  #pragma unroll
  for (int i = 0; i < 3; i++) {
    int off = wid * 3072 + i * 1024 + lane * 16;
    int rw = off / KROW_B, c = off - rw * KROW_B;
    ldso[i] = off;
    srco[i] = rw * KROW_B + (c ^ ((rw & 7) << 4));
  }
  const char* kgbase = (const char*)(Kb + ((size_t)(b * NN + n0)) * AA);

  int sw = (row & 7) << 4;
  int rbase = row * KROW_B;
  int x0 = rbase + ((hi * 16) ^ sw);
  int x1 = rbase + (((hi * 16) + 64) ^ sw);

  float zacc[NH][4];
  #pragma unroll
  for (int h = 0; h < NH; h++)
    #pragma unroll
    for (int j = 0; j < 4; j++) zacc[h][j] = 0.f;

  #pragma unroll
  for (int i = 0; i < 3; i++) ld_lds16(kgbase + srco[i], kbuf[0] + ldso[i]);
  __syncthreads();

  #pragma unroll 1
  for (int nt = 0; nt < 16; nt++) {
    int cur = nt & 1;
    if (nt < 15) {
      const char* src = kgbase + (size_t)(nt + 1) * TILE_B;
      #pragma unroll
      for (int i = 0; i < 3; i++) ld_lds16(src + srco[i], kbuf[cur ^ 1] + ldso[i]);
    }
    const char* kb = kbuf[cur];
    #pragma unroll
    for (int h = 0; h < NH; h++) {
      bf16x8 k0 = *reinterpret_cast<const bf16x8*>(kb + h * 128 + x0);
      bf16x8 k1 = *reinterpret_cast<const bf16x8*>(kb + h * 128 + x1);
      f32x4 acc = {0.f, 0.f, 0.f, 0.f};
      acc = mfma16(qf[2 * h], k0, acc);
      acc = mfma16(qf[2 * h + 1], k1, acc);
      #pragma unroll
      for (int j = 0; j < 4; j++) zacc[h][j] += __expf(acc[j]);
    }
    __syncthreads();
  }

  #pragma unroll
  for (int h = 0; h < NH; h++)
    #pragma unroll
    for (int j = 0; j < 4; j++) {
      float v = zacc[h][j];
      v += __shfl_xor(v, 1); v += __shfl_xor(v, 2);
      v += __shfl_xor(v, 4); v += __shfl_xor(v, 8);
      zacc[h][j] = v;
    }
  if (row == 0) {
    #pragma unroll
    for (int h = 0; h < NH; h++)
      #pragma unroll
      for (int j = 0; j < 4; j++)
        Zp[(((size_t)nc * 8 + b) * NH + h) * MM + m0 + hi * 4 + j] = zacc[h][j];
  }
}

// ---------------- pass 2: normalized head-combined weights W[b][m][n] bf16 ----------------
__global__ __launch_bounds__(256) void wpass_kernel(
    const bf16* __restrict__ Qb, const bf16* __restrict__ Kb,
    const float* __restrict__ Zp, bf16* __restrict__ W)
{
  __shared__ char kbuf[2][TILE_B];
  int id = blockIdx.x;
  int b = id & 7, r = id >> 3, mt = r & 15, nc = r >> 4;
  int tid = threadIdx.x, wid = tid >> 6, lane = tid & 63;
  int m0 = mt * 64 + wid * 16, n0 = nc * 256;
  int row = lane & 15, hi = lane >> 4;

  bf16x8 qf[12];
  const bf16* qrow = Qb + ((size_t)(b * MM + m0 + row)) * AA + hi * 8;
  #pragma unroll
  for (int ks = 0; ks < 12; ks++) qf[ks] = *reinterpret_cast<const bf16x8*>(qrow + ks * 32);

  float rz[NH][4];
  #pragma unroll
  for (int h = 0; h < NH; h++)
    #pragma unroll
    for (int j = 0; j < 4; j++) {
      int m = m0 + hi * 4 + j;
      float z = 0.f;
      #pragma unroll
      for (int p = 0; p < 8; p++) z += Zp[(((size_t)p * 8 + b) * NH + h) * MM + m];
      rz[h][j] = 1.0f / (6.0f * z);
    }

  int ldso[3], srco[3];
  #pragma unroll
  for (int i = 0; i < 3; i++) {
    int off = wid * 3072 + i * 1024 + lane * 16;
    int rw = off / KROW_B, c = off - rw * KROW_B;
    ldso[i] = off;
    srco[i] = rw * KROW_B + (c ^ ((rw & 7) << 4));
  }
  const char* kgbase = (const char*)(Kb + ((size_t)(b * NN + n0)) * AA);

  int sw = (row & 7) << 4;
  int rbase = row * KROW_B;
  int x0 = rbase + ((hi * 16) ^ sw);
  int x1 = rbase + (((hi * 16) + 64) ^ sw);

  #pragma unroll
  for (int i = 0; i < 3; i++) ld_lds16(kgbase + srco[i], kbuf[0] + ldso[i]);
  __syncthreads();

  #pragma unroll 1
  for (int nt = 0; nt < 16; nt++) {
    int cur = nt & 1;
    if (nt < 15) {
      const char* src = kgbase + (size_t)(nt + 1) * TILE_B;
      #pragma unroll
      for (int i = 0; i < 3; i++) ld_lds16(src + srco[i], kbuf[cur ^ 1] + ldso[i]);
    }
    const char* kb = kbuf[cur];
    float w0 = 0.f, w1 = 0.f, w2 = 0.f, w3 = 0.f;
    #pragma unroll
    for (int h = 0; h < NH; h++) {
      bf16x8 k0 = *reinterpret_cast<const bf16x8*>(kb + h * 128 + x0);
      bf16x8 k1 = *reinterpret_cast<const bf16x8*>(kb + h * 128 + x1);
      f32x4 acc = {0.f, 0.f, 0.f, 0.f};
      acc = mfma16(qf[2 * h], k0, acc);
      acc = mfma16(qf[2 * h + 1], k1, acc);
      w0 += __expf(acc[0]) * rz[h][0];
      w1 += __expf(acc[1]) * rz[h][1];
      w2 += __expf(acc[2]) * rz[h][2];
      w3 += __expf(acc[3]) * rz[h][3];
    }
    int n = n0 + nt * 16 + row;
    size_t base = ((size_t)(b * MM + m0 + hi * 4)) * NN + n;
    W[base]          = __float2bfloat16(w0);
    W[base + NN]     = __float2bfloat16(w1);
    W[base + 2 * NN] = __float2bfloat16(w2);
    W[base + 3 * NN] = __float2bfloat16(w3);
    __syncthreads();
  }
}

// ---------------- pass 3: CSR gather + log ----------------
__global__ __launch_bounds__(512) void gather_kernel(
    const bf16* __restrict__ W, const int* __restrict__ offs,
    const int* __restrict__ idxs, float* __restrict__ out)
{
  __shared__ bf16 wl[16 * NN];          // 64 KB
  int id = blockIdx.x;
  int b = id & 7, mt = id >> 3;
  int m0 = mt * 16;
  int tid = threadIdx.x;

  const uint4* src = (const uint4*)(W + ((size_t)(b * MM + m0)) * NN);
  uint4* dst = (uint4*)wl;
  #pragma unroll
  for (int i = tid; i < 16 * NN / 8; i += 512) dst[i] = src[i];
  __syncthreads();

  int c = tid;
  int o0 = offs[b * (CC + 1) + c], o1 = offs[b * (CC + 1) + c + 1];
  const int* il = idxs + b * NN;
  #pragma unroll 1
  for (int mi = 0; mi < 16; mi++) {
    float s = 0.f;
    for (int i = o0; i < o1; i++) s += __bfloat162float(wl[mi * NN + il[i]]);
    out[((size_t)(m0 + mi) * BQ + b) * CC + c] = __logf(fmaxf(s, 1e-5f) + 3e-5f);
  }
}

extern "C" void kernel_launch(void* const* d_in, const int* in_sizes, int n_in,
                              void* d_out, int out_size, void* d_ws, size_t ws_size,
                              hipStream_t stream) {
  const float* train = (const float*)d_in[0];
  const float* test  = (const float*)d_in[1];
  const int*   tgt   = (const int*)d_in[2];
  const float* Wq    = (const float*)d_in[3];
  const float* bq    = (const float*)d_in[4];
  const float* Wk    = (const float*)d_in[5];
  const float* bk    = (const float*)d_in[6];
  float* out = (float*)d_out;

  char* ws = (char*)d_ws;
  bf16*  WqT  = (bf16*)(ws);                       //    393,216 B
  bf16*  WkT  = (bf16*)(ws + 393216);              //    393,216 B
  bf16*  Qb   = (bf16*)(ws + 786432);              //  6,291,456 B
  bf16*  Kb   = (bf16*)(ws + 7077888);             // 12,582,912 B
  float* Zp   = (float*)(ws + 19660800);           //  1,572,864 B
  bf16*  Wbuf = (bf16*)(ws + 21233664);            // 33,554,432 B
  int*   offs = (int*)(ws + 54788096);             //     16,416 B
  int*   idxs = (int*)(ws + 54804512);             //     65,536 B

  transw_kernel<<<(EE * AA + 255) / 256, 256, 0, stream>>>(Wq, WqT);
  transw_kernel<<<(EE * AA + 255) / 256, 256, 0, stream>>>(Wk, WkT);
  build_kernel<<<BQ, 512, 0, stream>>>(tgt, offs, idxs);
  proj_kernel<<<768, 256, 0, stream>>>(test, train, WqT, WkT, bq, bk, Qb, Kb);
  zpass_kernel<<<1024, 256, 0, stream>>>(Qb, Kb, Zp);
  wpass_kernel<<<1024, 256, 0, stream>>>(Qb, Kb, Zp, Wbuf);
  gather_kernel<<<512, 512, 0, stream>>>(Wbuf, offs, idxs, out);
}

// Round 5
// 136.848 us; speedup vs baseline: 2.3403x; 1.0842x over previous
//
#include <hip/hip_runtime.h>
#include <hip/hip_bf16.h>

#define BQ 8      // batches
#define NN 2048   // train rows (keys)
#define MM 1024   // test rows (queries)
#define EE 512    // input size
#define NH 6      // heads
#define AA 384    // attn size (NH*64)
#define CC 512    // classes

#define KROW_B (AA * 2)          // 768 bytes per K row
#define TILE_B (16 * KROW_B)     // 12288 bytes per 16-row K tile
#define WROW_B (EE * 2)          // 1024 bytes per W row
#define WTILE_B (16 * WROW_B)    // 16384 bytes per 16-row W tile

typedef __bf16 bf16x8 __attribute__((ext_vector_type(8)));
typedef float  f32x4  __attribute__((ext_vector_type(4)));
using bf16 = __hip_bfloat16;

static __device__ __forceinline__ f32x4 mfma16(bf16x8 a, bf16x8 b, f32x4 c) {
  return __builtin_amdgcn_mfma_f32_16x16x32_bf16(a, b, c, 0, 0, 0);
}

typedef __attribute__((address_space(1))) const void gconst_void;
typedef __attribute__((address_space(3))) void lds_void_t;
static __device__ __forceinline__ void ld_lds16(const void* g, void* l) {
  __builtin_amdgcn_global_load_lds((gconst_void*)g, (lds_void_t*)l, 16, 0, 0);
}

// ---------------- W[K][N] -> WT[N][K] bf16 ----------------
__global__ void transw_kernel(const float* __restrict__ W, bf16* __restrict__ WT) {
  int i = blockIdx.x * blockDim.x + threadIdx.x;
  if (i < EE * AA) {
    int k = i / AA, n = i - k * AA;
    WT[n * EE + k] = __float2bfloat16(W[i]);
  }
}

// ---------------- CSR build ----------------
__global__ __launch_bounds__(512) void build_kernel(const int* __restrict__ targets,
                                                    int* __restrict__ offs, int* __restrict__ idxs) {
  __shared__ int cnt[CC], ssum[CC], pos[CC];
  int b = blockIdx.x, tid = threadIdx.x;
  cnt[tid] = 0;
  __syncthreads();
  int t[4];
  #pragma unroll
  for (int i = 0; i < 4; i++) {
    t[i] = targets[b * NN + tid * 4 + i];
    atomicAdd(&cnt[t[i]], 1);
  }
  __syncthreads();
  ssum[tid] = cnt[tid];
  __syncthreads();
  for (int d = 1; d < CC; d <<= 1) {
    int v = (tid >= d) ? ssum[tid - d] : 0;
    __syncthreads();
    ssum[tid] += v;
    __syncthreads();
  }
  int excl = ssum[tid] - cnt[tid];
  offs[b * (CC + 1) + tid] = excl;
  if (tid == CC - 1) offs[b * (CC + 1) + CC] = NN;
  pos[tid] = excl;
  __syncthreads();
  #pragma unroll
  for (int i = 0; i < 4; i++) {
    int p = atomicAdd(&pos[t[i]], 1);
    idxs[b * NN + p] = tid * 4 + i;
  }
}

// ---------------- projections (f32 in, bf16 out), 3-deep counted-vmcnt pipeline ----------------
// grid = 768: (128 Q-units + 256 K-units of 64 rows) x 2 n-halves
__global__ __launch_bounds__(256, 3) void proj_kernel(
    const float* __restrict__ test, const float* __restrict__ train,
    const bf16* __restrict__ WqT, const bf16* __restrict__ WkT,
    const float* __restrict__ bq, const float* __restrict__ bk,
    bf16* __restrict__ Qb, bf16* __restrict__ Kb)
{
  __shared__ char wbuf[3][WTILE_B];   // 48 KB
  int tid = threadIdx.x, wid = tid >> 6, lane = tid & 63;
  int bid = blockIdx.x;
  int sub = bid & 1, unit = bid >> 1;
  const float* A; const bf16* WT; const float* bias; bf16* C; float scale; int m0;
  if (unit < 128) { A = test;  WT = WqT; bias = bq; C = Qb; scale = 0.125f; m0 = unit * 64; }
  else            { A = train; WT = WkT; bias = bk; C = Kb; scale = 1.0f;   m0 = (unit - 128) * 64; }
  m0 += wid * 16;
  int row = lane & 15, hi = lane >> 4;

  // A fragments: f32 -> bf16, 16 rows x 512 k per wave
  bf16x8 af[16];
  const float* arow = A + (size_t)(m0 + row) * EE + hi * 8;
  #pragma unroll
  for (int ks = 0; ks < 16; ks++) {
    float4 u = *reinterpret_cast<const float4*>(arow + ks * 32);
    float4 v = *reinterpret_cast<const float4*>(arow + ks * 32 + 4);
    bf16x8 f;
    f[0] = (__bf16)u.x; f[1] = (__bf16)u.y; f[2] = (__bf16)u.z; f[3] = (__bf16)u.w;
    f[4] = (__bf16)v.x; f[5] = (__bf16)v.y; f[6] = (__bf16)v.z; f[7] = (__bf16)v.w;
    af[ks] = f;
  }

  // staging offsets: 4 x 16B per thread; linear LDS dest, inverse-swizzled source
  int ldso[4], srco[4];
  #pragma unroll
  for (int i = 0; i < 4; i++) {
    int off = tid * 16 + i * 4096;
    int rw = off >> 10, c = off & 1023;
    ldso[i] = off;
    srco[i] = rw * WROW_B + (c ^ ((rw & 7) << 4));
  }
  const char* wgbase = (const char*)WT + (size_t)sub * 12 * WTILE_B;
  int sw = (row & 7) << 4;

  auto compute = [&](const char* base, int t) {
    const char* wb = base + row * WROW_B;
    f32x4 acc0 = {0.f, 0.f, 0.f, 0.f}, acc1 = {0.f, 0.f, 0.f, 0.f};
    #pragma unroll
    for (int ks = 0; ks < 16; ks += 2) {
      bf16x8 w0 = *reinterpret_cast<const bf16x8*>(wb + ((hi * 16 + ks * 64) ^ sw));
      bf16x8 w1 = *reinterpret_cast<const bf16x8*>(wb + ((hi * 16 + (ks + 1) * 64) ^ sw));
      acc0 = mfma16(af[ks], w0, acc0);
      acc1 = mfma16(af[ks + 1], w1, acc1);
    }
    f32x4 acc = acc0 + acc1;
    int ocol = (sub * 12 + t) * 16 + row;
    float bv = bias[ocol];
    #pragma unroll
    for (int j = 0; j < 4; j++)
      C[(size_t)(m0 + hi * 4 + j) * AA + ocol] = __float2bfloat16((acc[j] + bv) * scale);
  };

  // prologue: stage tiles 0,1
  #pragma unroll
  for (int i = 0; i < 4; i++) ld_lds16(wgbase + srco[i], wbuf[0] + ldso[i]);
  #pragma unroll
  for (int i = 0; i < 4; i++) ld_lds16(wgbase + WTILE_B + srco[i], wbuf[1] + ldso[i]);

  int cur = 0, stg = 2;
  #pragma unroll 1
  for (int t = 0; t < 11; t++) {
    asm volatile("s_waitcnt vmcnt(4)" ::: "memory");   // tile t landed; t+1 in flight
    __builtin_amdgcn_s_barrier();
    __builtin_amdgcn_sched_barrier(0);
    if (t < 10) {                                      // stage tile t+2
      const char* src = wgbase + (size_t)(t + 2) * WTILE_B;
      #pragma unroll
      for (int i = 0; i < 4; i++) ld_lds16(src + srco[i], wbuf[stg] + ldso[i]);
    }
    compute(wbuf[cur], t);
    cur = cur + 1 < 3 ? cur + 1 : 0;
    stg = stg + 1 < 3 ? stg + 1 : 0;
  }
  asm volatile("s_waitcnt vmcnt(0)" ::: "memory");
  __builtin_amdgcn_s_barrier();
  __builtin_amdgcn_sched_barrier(0);
  compute(wbuf[cur], 11);
}

// ---------------- pass 1: Z partials. grid = 8b x 16mt(64m) x 8nc(256n) = 1024 ----------------
__global__ __launch_bounds__(256, 4) void zpass_kernel(
    const bf16* __restrict__ Qb, const bf16* __restrict__ Kb, float* __restrict__ Zp)
{
  __shared__ char kbuf[3][TILE_B];    // 36 KB
  int id = blockIdx.x;
  int b = id & 7, r = id >> 3, mt = r & 15, nc = r >> 4;
  int tid = threadIdx.x, wid = tid >> 6, lane = tid & 63;
  int m0 = mt * 64 + wid * 16, n0 = nc * 256;
  int row = lane & 15, hi = lane >> 4;

  bf16x8 qf[12];
  const bf16* qrow = Qb + ((size_t)(b * MM + m0 + row)) * AA + hi * 8;
  #pragma unroll
  for (int ks = 0; ks < 12; ks++) qf[ks] = *reinterpret_cast<const bf16x8*>(qrow + ks * 32);

  int ldso[3], srco[3];
  #pragma unroll
  for (int i = 0; i < 3; i++) {
    int off = wid * 3072 + i * 1024 + lane * 16;
    int rw = off / KROW_B, c = off - rw * KROW_B;
    ldso[i] = off;
    srco[i] = rw * KROW_B + (c ^ ((rw & 7) << 4));
  }
  const char* kgbase = (const char*)(Kb + ((size_t)(b * NN + n0)) * AA);

  int sw = (row & 7) << 4;
  int rbase = row * KROW_B;
  int x0 = rbase + ((hi * 16) ^ sw);
  int x1 = rbase + (((hi * 16) + 64) ^ sw);

  float zacc[NH][4];
  #pragma unroll
  for (int h = 0; h < NH; h++)
    #pragma unroll
    for (int j = 0; j < 4; j++) zacc[h][j] = 0.f;

  auto compute = [&](const char* kb) {
    #pragma unroll
    for (int h = 0; h < NH; h++) {
      bf16x8 k0 = *reinterpret_cast<const bf16x8*>(kb + h * 128 + x0);
      bf16x8 k1 = *reinterpret_cast<const bf16x8*>(kb + h * 128 + x1);
      f32x4 acc = {0.f, 0.f, 0.f, 0.f};
      acc = mfma16(qf[2 * h], k0, acc);
      acc = mfma16(qf[2 * h + 1], k1, acc);
      #pragma unroll
      for (int j = 0; j < 4; j++) zacc[h][j] += __expf(acc[j]);
    }
  };

  #pragma unroll
  for (int i = 0; i < 3; i++) ld_lds16(kgbase + srco[i], kbuf[0] + ldso[i]);
  #pragma unroll
  for (int i = 0; i < 3; i++) ld_lds16(kgbase + TILE_B + srco[i], kbuf[1] + ldso[i]);

  int cur = 0, stg = 2;
  #pragma unroll 1
  for (int nt = 0; nt < 15; nt++) {
    asm volatile("s_waitcnt vmcnt(3)" ::: "memory");   // tile nt landed; nt+1 in flight
    __builtin_amdgcn_s_barrier();
    __builtin_amdgcn_sched_barrier(0);
    if (nt < 14) {                                     // stage tile nt+2
      const char* src = kgbase + (size_t)(nt + 2) * TILE_B;
      #pragma unroll
      for (int i = 0; i < 3; i++) ld_lds16(src + srco[i], kbuf[stg] + ldso[i]);
    }
    compute(kbuf[cur]);
    cur = cur + 1 < 3 ? cur + 1 : 0;
    stg = stg + 1 < 3 ? stg + 1 : 0;
  }
  asm volatile("s_waitcnt vmcnt(0)" ::: "memory");
  __builtin_amdgcn_s_barrier();
  __builtin_amdgcn_sched_barrier(0);
  compute(kbuf[cur]);

  #pragma unroll
  for (int h = 0; h < NH; h++)
    #pragma unroll
    for (int j = 0; j < 4; j++) {
      float v = zacc[h][j];
      v += __shfl_xor(v, 1); v += __shfl_xor(v, 2);
      v += __shfl_xor(v, 4); v += __shfl_xor(v, 8);
      zacc[h][j] = v;
    }
  if (row == 0) {
    #pragma unroll
    for (int h = 0; h < NH; h++)
      #pragma unroll
      for (int j = 0; j < 4; j++)
        Zp[(((size_t)nc * 8 + b) * NH + h) * MM + m0 + hi * 4 + j] = zacc[h][j];
  }
}

// ---------------- pass 2: normalized head-combined weights W[b][m][n] bf16 ----------------
__global__ __launch_bounds__(256, 4) void wpass_kernel(
    const bf16* __restrict__ Qb, const bf16* __restrict__ Kb,
    const float* __restrict__ Zp, bf16* __restrict__ W)
{
  __shared__ char kbuf[3][TILE_B];    // 36 KB
  int id = blockIdx.x;
  int b = id & 7, r = id >> 3, mt = r & 15, nc = r >> 4;
  int tid = threadIdx.x, wid = tid >> 6, lane = tid & 63;
  int m0 = mt * 64 + wid * 16, n0 = nc * 256;
  int row = lane & 15, hi = lane >> 4;

  bf16x8 qf[12];
  const bf16* qrow = Qb + ((size_t)(b * MM + m0 + row)) * AA + hi * 8;
  #pragma unroll
  for (int ks = 0; ks < 12; ks++) qf[ks] = *reinterpret_cast<const bf16x8*>(qrow + ks * 32);

  float rz[NH][4];
  #pragma unroll
  for (int h = 0; h < NH; h++)
    #pragma unroll
    for (int j = 0; j < 4; j++) {
      int m = m0 + hi * 4 + j;
      float z = 0.f;
      #pragma unroll
      for (int p = 0; p < 8; p++) z += Zp[(((size_t)p * 8 + b) * NH + h) * MM + m];
      rz[h][j] = 1.0f / (6.0f * z);
    }

  int ldso[3], srco[3];
  #pragma unroll
  for (int i = 0; i < 3; i++) {
    int off = wid * 3072 + i * 1024 + lane * 16;
    int rw = off / KROW_B, c = off - rw * KROW_B;
    ldso[i] = off;
    srco[i] = rw * KROW_B + (c ^ ((rw & 7) << 4));
  }
  const char* kgbase = (const char*)(Kb + ((size_t)(b * NN + n0)) * AA);

  int sw = (row & 7) << 4;
  int rbase = row * KROW_B;
  int x0 = rbase + ((hi * 16) ^ sw);
  int x1 = rbase + (((hi * 16) + 64) ^ sw);

  auto compute = [&](const char* kb, int nt) {
    float w0 = 0.f, w1 = 0.f, w2 = 0.f, w3 = 0.f;
    #pragma unroll
    for (int h = 0; h < NH; h++) {
      bf16x8 k0 = *reinterpret_cast<const bf16x8*>(kb + h * 128 + x0);
      bf16x8 k1 = *reinterpret_cast<const bf16x8*>(kb + h * 128 + x1);
      f32x4 acc = {0.f, 0.f, 0.f, 0.f};
      acc = mfma16(qf[2 * h], k0, acc);
      acc = mfma16(qf[2 * h + 1], k1, acc);
      w0 += __expf(acc[0]) * rz[h][0];
      w1 += __expf(acc[1]) * rz[h][1];
      w2 += __expf(acc[2]) * rz[h][2];
      w3 += __expf(acc[3]) * rz[h][3];
    }
    int n = n0 + nt * 16 + row;
    size_t base = ((size_t)(b * MM + m0 + hi * 4)) * NN + n;
    W[base]          = __float2bfloat16(w0);
    W[base + NN]     = __float2bfloat16(w1);
    W[base + 2 * NN] = __float2bfloat16(w2);
    W[base + 3 * NN] = __float2bfloat16(w3);
  };

  #pragma unroll
  for (int i = 0; i < 3; i++) ld_lds16(kgbase + srco[i], kbuf[0] + ldso[i]);
  #pragma unroll
  for (int i = 0; i < 3; i++) ld_lds16(kgbase + TILE_B + srco[i], kbuf[1] + ldso[i]);

  int cur = 0, stg = 2;
  #pragma unroll 1
  for (int nt = 0; nt < 15; nt++) {
    asm volatile("s_waitcnt vmcnt(3)" ::: "memory");
    __builtin_amdgcn_s_barrier();
    __builtin_amdgcn_sched_barrier(0);
    if (nt < 14) {
      const char* src = kgbase + (size_t)(nt + 2) * TILE_B;
      #pragma unroll
      for (int i = 0; i < 3; i++) ld_lds16(src + srco[i], kbuf[stg] + ldso[i]);
    }
    compute(kbuf[cur], nt);
    cur = cur + 1 < 3 ? cur + 1 : 0;
    stg = stg + 1 < 3 ? stg + 1 : 0;
  }
  asm volatile("s_waitcnt vmcnt(0)" ::: "memory");
  __builtin_amdgcn_s_barrier();
  __builtin_amdgcn_sched_barrier(0);
  compute(kbuf[cur], 15);
}

// ---------------- pass 3: CSR gather + log ----------------
__global__ __launch_bounds__(512) void gather_kernel(
    const bf16* __restrict__ W, const int* __restrict__ offs,
    const int* __restrict__ idxs, float* __restrict__ out)
{
  __shared__ bf16 wl[16 * NN];          // 64 KB
  int id = blockIdx.x;
  int b = id & 7, mt = id >> 3;
  int m0 = mt * 16;
  int tid = threadIdx.x;

  const uint4* src = (const uint4*)(W + ((size_t)(b * MM + m0)) * NN);
  uint4* dst = (uint4*)wl;
  #pragma unroll
  for (int i = tid; i < 16 * NN / 8; i += 512) dst[i] = src[i];
  __syncthreads();

  int c = tid;
  int o0 = offs[b * (CC + 1) + c], o1 = offs[b * (CC + 1) + c + 1];
  const int* il = idxs + b * NN;
  #pragma unroll 1
  for (int mi = 0; mi < 16; mi++) {
    float s = 0.f;
    for (int i = o0; i < o1; i++) s += __bfloat162float(wl[mi * NN + il[i]]);
    out[((size_t)(m0 + mi) * BQ + b) * CC + c] = __logf(fmaxf(s, 1e-5f) + 3e-5f);
  }
}

extern "C" void kernel_launch(void* const* d_in, const int* in_sizes, int n_in,
                              void* d_out, int out_size, void* d_ws, size_t ws_size,
                              hipStream_t stream) {
  const float* train = (const float*)d_in[0];
  const float* test  = (const float*)d_in[1];
  const int*   tgt   = (const int*)d_in[2];
  const float* Wq    = (const float*)d_in[3];
  const float* bq    = (const float*)d_in[4];
  const float* Wk    = (const float*)d_in[5];
  const float* bk    = (const float*)d_in[6];
  float* out = (float*)d_out;

  char* ws = (char*)d_ws;
  bf16*  WqT  = (bf16*)(ws);                       //    393,216 B
  bf16*  WkT  = (bf16*)(ws + 393216);              //    393,216 B
  bf16*  Qb   = (bf16*)(ws + 786432);              //  6,291,456 B
  bf16*  Kb   = (bf16*)(ws + 7077888);             // 12,582,912 B
  float* Zp   = (float*)(ws + 19660800);           //  1,572,864 B
  bf16*  Wbuf = (bf16*)(ws + 21233664);            // 33,554,432 B
  int*   offs = (int*)(ws + 54788096);             //     16,416 B
  int*   idxs = (int*)(ws + 54804512);             //     65,536 B

  transw_kernel<<<(EE * AA + 255) / 256, 256, 0, stream>>>(Wq, WqT);
  transw_kernel<<<(EE * AA + 255) / 256, 256, 0, stream>>>(Wk, WkT);
  build_kernel<<<BQ, 512, 0, stream>>>(tgt, offs, idxs);
  proj_kernel<<<768, 256, 0, stream>>>(test, train, WqT, WkT, bq, bk, Qb, Kb);
  zpass_kernel<<<1024, 256, 0, stream>>>(Qb, Kb, Zp);
  wpass_kernel<<<1024, 256, 0, stream>>>(Qb, Kb, Zp, Wbuf);
  gather_kernel<<<512, 512, 0, stream>>>(Wbuf, offs, idxs, out);
}

// Round 6
// 112.842 us; speedup vs baseline: 2.8382x; 1.2127x over previous
//
#include <hip/hip_runtime.h>
#include <hip/hip_bf16.h>

#define BQ 8      // batches
#define NN 2048   // train rows (keys)
#define MM 1024   // test rows (queries)
#define EE 512    // input size
#define NH 6      // heads
#define AA 384    // attn size (NH*64)
#define CC 512    // classes

#define KROW_B (AA * 2)          // 768 bytes per K row
#define TILE_B (16 * KROW_B)     // 12288 bytes per 16-row K tile
#define WROW_B (EE * 2)          // 1024 bytes per W row
#define WTILE_B (16 * WROW_B)    // 16384 bytes per 16-row W tile

// fold SDPA scale and log2(e) into Q so score passes use raw v_exp_f32 (exp2)
#define QSCALE 0.1803368801111204f   // 0.125 * log2(e)

typedef __bf16 bf16x8 __attribute__((ext_vector_type(8)));
typedef float  f32x4  __attribute__((ext_vector_type(4)));
using bf16 = __hip_bfloat16;

static __device__ __forceinline__ f32x4 mfma16(bf16x8 a, bf16x8 b, f32x4 c) {
  return __builtin_amdgcn_mfma_f32_16x16x32_bf16(a, b, c, 0, 0, 0);
}

typedef __attribute__((address_space(1))) const void gconst_void;
typedef __attribute__((address_space(3))) void lds_void_t;
static __device__ __forceinline__ void ld_lds16(const void* g, void* l) {
  __builtin_amdgcn_global_load_lds((gconst_void*)g, (lds_void_t*)l, 16, 0, 0);
}

static __device__ __forceinline__ unsigned short f2bfu(float x) {
  union { __hip_bfloat16 h; unsigned short u; } v;
  v.h = __float2bfloat16(x);
  return v.u;
}
static __device__ __forceinline__ float bf2f(unsigned short u) {
  union { unsigned int i; float f; } x;
  x.i = ((unsigned int)u) << 16;
  return x.f;
}

// ---------------- W[K][N] -> WT[N][K] bf16, LDS tile transpose ----------------
// grid = 8x6 = 48 blocks, each 64k x 64n tile
__global__ __launch_bounds__(256) void transw_kernel(const float* __restrict__ W, bf16* __restrict__ WT) {
  __shared__ float t[64][65];
  int kb = (blockIdx.x / 6) * 64, nb = (blockIdx.x % 6) * 64;
  int tid = threadIdx.x;
  int lr = tid >> 4, lc = (tid & 15) * 4;      // 16 rows x 64 cols per pass
  #pragma unroll
  for (int p = 0; p < 4; p++) {
    int k = lr + p * 16;
    float4 v = *reinterpret_cast<const float4*>(W + (size_t)(kb + k) * AA + nb + lc);
    t[k][lc] = v.x; t[k][lc + 1] = v.y; t[k][lc + 2] = v.z; t[k][lc + 3] = v.w;
  }
  __syncthreads();
  #pragma unroll
  for (int p = 0; p < 4; p++) {
    int n = lr + p * 16;
    bf16* dst = WT + (size_t)(nb + n) * EE + kb + lc;
    dst[0] = __float2bfloat16(t[lc][n]);
    dst[1] = __float2bfloat16(t[lc + 1][n]);
    dst[2] = __float2bfloat16(t[lc + 2][n]);
    dst[3] = __float2bfloat16(t[lc + 3][n]);
  }
}

// ---------------- CSR build ----------------
__global__ __launch_bounds__(512) void build_kernel(const int* __restrict__ targets,
                                                    int* __restrict__ offs, int* __restrict__ idxs) {
  __shared__ int cnt[CC], ssum[CC], pos[CC];
  int b = blockIdx.x, tid = threadIdx.x;
  cnt[tid] = 0;
  __syncthreads();
  int t[4];
  #pragma unroll
  for (int i = 0; i < 4; i++) {
    t[i] = targets[b * NN + tid * 4 + i];
    atomicAdd(&cnt[t[i]], 1);
  }
  __syncthreads();
  ssum[tid] = cnt[tid];
  __syncthreads();
  for (int d = 1; d < CC; d <<= 1) {
    int v = (tid >= d) ? ssum[tid - d] : 0;
    __syncthreads();
    ssum[tid] += v;
    __syncthreads();
  }
  int excl = ssum[tid] - cnt[tid];
  offs[b * (CC + 1) + tid] = excl;
  if (tid == CC - 1) offs[b * (CC + 1) + CC] = NN;
  pos[tid] = excl;
  __syncthreads();
  #pragma unroll
  for (int i = 0; i < 4; i++) {
    int p = atomicAdd(&pos[t[i]], 1);
    idxs[b * NN + p] = tid * 4 + i;
  }
}

// ---------------- projections (f32 in, bf16 out), 3-deep store-aware pipeline ----------------
// grid = 768: (128 Q-units + 256 K-units of 64 rows) x 2 n-halves
__global__ __launch_bounds__(256, 3) void proj_kernel(
    const float* __restrict__ test, const float* __restrict__ train,
    const bf16* __restrict__ WqT, const bf16* __restrict__ WkT,
    const float* __restrict__ bq, const float* __restrict__ bk,
    bf16* __restrict__ Qb, bf16* __restrict__ Kb)
{
  __shared__ char wbuf[3][WTILE_B];   // 48 KB
  int tid = threadIdx.x, wid = tid >> 6, lane = tid & 63;
  int bid = blockIdx.x;
  int sub = bid & 1, unit = bid >> 1;
  const float* A; const bf16* WT; const float* bias; bf16* C; float scale; int m0;
  if (unit < 128) { A = test;  WT = WqT; bias = bq; C = Qb; scale = QSCALE; m0 = unit * 64; }
  else            { A = train; WT = WkT; bias = bk; C = Kb; scale = 1.0f;   m0 = (unit - 128) * 64; }
  m0 += wid * 16;
  int row = lane & 15, hi = lane >> 4;

  // A fragments: f32 -> bf16, 16 rows x 512 k per wave (32 float4 loads)
  bf16x8 af[16];
  const float* arow = A + (size_t)(m0 + row) * EE + hi * 8;
  #pragma unroll
  for (int ks = 0; ks < 16; ks++) {
    float4 u = *reinterpret_cast<const float4*>(arow + ks * 32);
    float4 v = *reinterpret_cast<const float4*>(arow + ks * 32 + 4);
    bf16x8 f;
    f[0] = (__bf16)u.x; f[1] = (__bf16)u.y; f[2] = (__bf16)u.z; f[3] = (__bf16)u.w;
    f[4] = (__bf16)v.x; f[5] = (__bf16)v.y; f[6] = (__bf16)v.z; f[7] = (__bf16)v.w;
    af[ks] = f;
  }

  int ldso[4], srco[4];
  #pragma unroll
  for (int i = 0; i < 4; i++) {
    int off = tid * 16 + i * 4096;
    int rw = off >> 10, c = off & 1023;
    ldso[i] = off;
    srco[i] = rw * WROW_B + (c ^ ((rw & 7) << 4));
  }
  const char* wgbase = (const char*)WT + (size_t)sub * 12 * WTILE_B;
  int sw = (row & 7) << 4;

  auto stage = [&](int t, int buf) {
    const char* src = wgbase + (size_t)t * WTILE_B;
    #pragma unroll
    for (int i = 0; i < 4; i++) ld_lds16(src + srco[i], wbuf[buf] + ldso[i]);
  };
  auto compute = [&](int buf, int t) {          // issues 4 x 2B stores
    const char* wb = wbuf[buf] + row * WROW_B;
    f32x4 acc0 = {0.f, 0.f, 0.f, 0.f}, acc1 = {0.f, 0.f, 0.f, 0.f};
    #pragma unroll
    for (int ks = 0; ks < 16; ks += 2) {
      bf16x8 w0 = *reinterpret_cast<const bf16x8*>(wb + ((hi * 16 + ks * 64) ^ sw));
      bf16x8 w1 = *reinterpret_cast<const bf16x8*>(wb + ((hi * 16 + (ks + 1) * 64) ^ sw));
      acc0 = mfma16(af[ks], w0, acc0);
      acc1 = mfma16(af[ks + 1], w1, acc1);
    }
    f32x4 acc = acc0 + acc1;
    int ocol = (sub * 12 + t) * 16 + row;
    float bv = bias[ocol];
    #pragma unroll
    for (int j = 0; j < 4; j++)
      C[(size_t)(m0 + hi * 4 + j) * AA + ocol] = __float2bfloat16((acc[j] + bv) * scale);
  };

  stage(0, 0);
  stage(1, 1);
  // iter 0 (loads-only in queue): wait T0
  asm volatile("s_waitcnt vmcnt(4)" ::: "memory");
  __builtin_amdgcn_s_barrier();
  __builtin_amdgcn_sched_barrier(0);
  stage(2, 2);
  compute(0, 0);

  int cur = 1, stg = 0;
  #pragma unroll 1
  for (int t = 1; t < 11; t++) {
    // steady: outstanding = T(t)(4 oldest) + [T(t+1), stores(t-1)](8) -> wait 8
    asm volatile("s_waitcnt vmcnt(8)" ::: "memory");
    __builtin_amdgcn_s_barrier();
    __builtin_amdgcn_sched_barrier(0);
    if (t < 10) stage(t + 2, stg);
    compute(cur, t);
    cur = cur + 1 < 3 ? cur + 1 : 0;
    stg = stg + 1 < 3 ? stg + 1 : 0;
  }
  // final: allow newest 4 (stores of iter 10) outstanding
  asm volatile("s_waitcnt vmcnt(4)" ::: "memory");
  __builtin_amdgcn_s_barrier();
  __builtin_amdgcn_sched_barrier(0);
  compute(cur, 11);
}

// ---------------- pass 1: Z partials. grid = 8b x 16mt(64m) x 8nc(256n) = 1024 ----------------
__global__ __launch_bounds__(256, 4) void zpass_kernel(
    const bf16* __restrict__ Qb, const bf16* __restrict__ Kb, float* __restrict__ Zp)
{
  __shared__ char kbuf[3][TILE_B];    // 36 KB
  int id = blockIdx.x;
  int b = id & 7, r = id >> 3, mt = r & 15, nc = r >> 4;
  int tid = threadIdx.x, wid = tid >> 6, lane = tid & 63;
  int m0 = mt * 64 + wid * 16, n0 = nc * 256;
  int row = lane & 15, hi = lane >> 4;

  bf16x8 qf[12];
  const bf16* qrow = Qb + ((size_t)(b * MM + m0 + row)) * AA + hi * 8;
  #pragma unroll
  for (int ks = 0; ks < 12; ks++) qf[ks] = *reinterpret_cast<const bf16x8*>(qrow + ks * 32);

  int ldso[3], srco[3];
  #pragma unroll
  for (int i = 0; i < 3; i++) {
    int off = wid * 3072 + i * 1024 + lane * 16;
    int rw = off / KROW_B, c = off - rw * KROW_B;
    ldso[i] = off;
    srco[i] = rw * KROW_B + (c ^ ((rw & 7) << 4));
  }
  const char* kgbase = (const char*)(Kb + ((size_t)(b * NN + n0)) * AA);

  int sw = (row & 7) << 4;
  int rbase = row * KROW_B;
  int x0 = rbase + ((hi * 16) ^ sw);
  int x1 = rbase + (((hi * 16) + 64) ^ sw);

  float zacc[NH][4];
  #pragma unroll
  for (int h = 0; h < NH; h++)
    #pragma unroll
    for (int j = 0; j < 4; j++) zacc[h][j] = 0.f;

  auto stage = [&](int t, int buf) {
    const char* src = kgbase + (size_t)t * TILE_B;
    #pragma unroll
    for (int i = 0; i < 3; i++) ld_lds16(src + srco[i], kbuf[buf] + ldso[i]);
  };
  auto compute = [&](int buf) {
    const char* kb = kbuf[buf];
    #pragma unroll
    for (int h = 0; h < NH; h++) {
      bf16x8 k0 = *reinterpret_cast<const bf16x8*>(kb + h * 128 + x0);
      bf16x8 k1 = *reinterpret_cast<const bf16x8*>(kb + h * 128 + x1);
      f32x4 acc = {0.f, 0.f, 0.f, 0.f};
      acc = mfma16(qf[2 * h], k0, acc);
      acc = mfma16(qf[2 * h + 1], k1, acc);
      #pragma unroll
      for (int j = 0; j < 4; j++) zacc[h][j] += __builtin_amdgcn_exp2f(acc[j]);
    }
  };

  stage(0, 0);
  stage(1, 1);
  int cur = 0, stg = 2;
  #pragma unroll 1
  for (int nt = 0; nt < 15; nt++) {
    asm volatile("s_waitcnt vmcnt(3)" ::: "memory");   // no stores in loop
    __builtin_amdgcn_s_barrier();
    __builtin_amdgcn_sched_barrier(0);
    if (nt < 14) stage(nt + 2, stg);
    compute(cur);
    cur = cur + 1 < 3 ? cur + 1 : 0;
    stg = stg + 1 < 3 ? stg + 1 : 0;
  }
  asm volatile("s_waitcnt vmcnt(0)" ::: "memory");
  __builtin_amdgcn_s_barrier();
  __builtin_amdgcn_sched_barrier(0);
  compute(cur);

  #pragma unroll
  for (int h = 0; h < NH; h++)
    #pragma unroll
    for (int j = 0; j < 4; j++) {
      float v = zacc[h][j];
      v += __shfl_xor(v, 1); v += __shfl_xor(v, 2);
      v += __shfl_xor(v, 4); v += __shfl_xor(v, 8);
      zacc[h][j] = v;
    }
  if (row == 0) {
    #pragma unroll
    for (int h = 0; h < NH; h++)
      #pragma unroll
      for (int j = 0; j < 4; j++)
        Zp[(((size_t)nc * 8 + b) * NH + h) * MM + m0 + hi * 4 + j] = zacc[h][j];
  }
}

// ---------------- pass 2: weights W2[b][m/4][n][4] bf16, store-aware pipeline ----------------
__global__ __launch_bounds__(256, 4) void wpass_kernel(
    const bf16* __restrict__ Qb, const bf16* __restrict__ Kb,
    const float* __restrict__ Zp, bf16* __restrict__ W2)
{
  __shared__ char kbuf[3][TILE_B];    // 36 KB
  int id = blockIdx.x;
  int b = id & 7, r = id >> 3, mt = r & 15, nc = r >> 4;
  int tid = threadIdx.x, wid = tid >> 6, lane = tid & 63;
  int m0 = mt * 64 + wid * 16, n0 = nc * 256;
  int row = lane & 15, hi = lane >> 4;

  bf16x8 qf[12];
  const bf16* qrow = Qb + ((size_t)(b * MM + m0 + row)) * AA + hi * 8;
  #pragma unroll
  for (int ks = 0; ks < 12; ks++) qf[ks] = *reinterpret_cast<const bf16x8*>(qrow + ks * 32);

  float rz[NH][4];
  #pragma unroll
  for (int h = 0; h < NH; h++) {
    f32x4 z = {0.f, 0.f, 0.f, 0.f};
    #pragma unroll
    for (int p = 0; p < 8; p++)
      z += *reinterpret_cast<const f32x4*>(Zp + (((size_t)p * 8 + b) * NH + h) * MM + m0 + hi * 4);
    #pragma unroll
    for (int j = 0; j < 4; j++) rz[h][j] = 1.0f / (6.0f * z[j]);
  }

  int ldso[3], srco[3];
  #pragma unroll
  for (int i = 0; i < 3; i++) {
    int off = wid * 3072 + i * 1024 + lane * 16;
    int rw = off / KROW_B, c = off - rw * KROW_B;
    ldso[i] = off;
    srco[i] = rw * KROW_B + (c ^ ((rw & 7) << 4));
  }
  const char* kgbase = (const char*)(Kb + ((size_t)(b * NN + n0)) * AA);

  int sw = (row & 7) << 4;
  int rbase = row * KROW_B;
  int x0 = rbase + ((hi * 16) ^ sw);
  int x1 = rbase + (((hi * 16) + 64) ^ sw);

  int m4 = (m0 >> 2) + hi;            // 4-row group index

  auto stage = [&](int t, int buf) {
    const char* src = kgbase + (size_t)t * TILE_B;
    #pragma unroll
    for (int i = 0; i < 3; i++) ld_lds16(src + srco[i], kbuf[buf] + ldso[i]);
  };
  auto compute = [&](int buf, int nt) {         // issues one 8B store
    const char* kb = kbuf[buf];
    float w0 = 0.f, w1 = 0.f, w2 = 0.f, w3 = 0.f;
    #pragma unroll
    for (int h = 0; h < NH; h++) {
      bf16x8 k0 = *reinterpret_cast<const bf16x8*>(kb + h * 128 + x0);
      bf16x8 k1 = *reinterpret_cast<const bf16x8*>(kb + h * 128 + x1);
      f32x4 acc = {0.f, 0.f, 0.f, 0.f};
      acc = mfma16(qf[2 * h], k0, acc);
      acc = mfma16(qf[2 * h + 1], k1, acc);
      w0 += __builtin_amdgcn_exp2f(acc[0]) * rz[h][0];
      w1 += __builtin_amdgcn_exp2f(acc[1]) * rz[h][1];
      w2 += __builtin_amdgcn_exp2f(acc[2]) * rz[h][2];
      w3 += __builtin_amdgcn_exp2f(acc[3]) * rz[h][3];
    }
    int n = n0 + nt * 16 + row;
    ushort4 q;
    q.x = f2bfu(w0); q.y = f2bfu(w1); q.z = f2bfu(w2); q.w = f2bfu(w3);
    *reinterpret_cast<ushort4*>((unsigned short*)W2 + (((size_t)(b * 256 + m4)) * NN + n) * 4) = q;
  };

  stage(0, 0);
  stage(1, 1);
  // iter 0 (loads-only queue): wait T0
  asm volatile("s_waitcnt vmcnt(3)" ::: "memory");
  __builtin_amdgcn_s_barrier();
  __builtin_amdgcn_sched_barrier(0);
  stage(2, 2);
  compute(0, 0);

  int cur = 1, stg = 0;
  #pragma unroll 1
  for (int nt = 1; nt < 15; nt++) {
    // steady: retire T(nt)+stores(nt-2); keep [T(nt+1), stores(nt-1)] = 7
    asm volatile("s_waitcnt vmcnt(7)" ::: "memory");
    __builtin_amdgcn_s_barrier();
    __builtin_amdgcn_sched_barrier(0);
    if (nt < 14) stage(nt + 2, stg);
    compute(cur, nt);
    cur = cur + 1 < 3 ? cur + 1 : 0;
    stg = stg + 1 < 3 ? stg + 1 : 0;
  }
  // final: allow newest 4 (stores of iter 14... 1 store x4 lanesets = 4 ops max) outstanding
  asm volatile("s_waitcnt vmcnt(4)" ::: "memory");
  __builtin_amdgcn_s_barrier();
  __builtin_amdgcn_sched_barrier(0);
  compute(cur, 15);
}

// ---------------- pass 3: CSR gather + log. grid = 8b x 128 m-chunks(8m) = 1024 ----------------
__global__ __launch_bounds__(512) void gather_kernel(
    const bf16* __restrict__ W2, const int* __restrict__ offs,
    const int* __restrict__ idxs, float* __restrict__ out)
{
  __shared__ char wl[2 * NN * 8];       // 2 m4-groups x 2048 n x 4 rows x 2B = 32 KB
  __shared__ int ilb[NN];               // 8 KB
  int id = blockIdx.x;
  int b = id & 7, mt = id >> 3;
  int g0 = mt * 2;                      // first m4 group
  int tid = threadIdx.x;

  const uint4* src = (const uint4*)((const unsigned short*)W2 + ((size_t)(b * 256 + g0)) * NN * 4);
  uint4* dst = (uint4*)wl;
  #pragma unroll
  for (int i = tid; i < 2 * NN * 8 / 16; i += 512) dst[i] = src[i];
  const int* il = idxs + b * NN;
  #pragma unroll
  for (int i = tid; i < NN; i += 512) ilb[i] = il[i];
  __syncthreads();

  int c = tid;
  int o0 = offs[b * (CC + 1) + c], o1 = offs[b * (CC + 1) + c + 1];
  #pragma unroll 1
  for (int g = 0; g < 2; g++) {
    float s0 = 0.f, s1 = 0.f, s2 = 0.f, s3 = 0.f;
    for (int i = o0; i < o1; i++) {
      int idx = ilb[i];
      ushort4 v = *reinterpret_cast<const ushort4*>(wl + g * (NN * 8) + idx * 8);
      s0 += bf2f(v.x); s1 += bf2f(v.y); s2 += bf2f(v.z); s3 += bf2f(v.w);
    }
    int m = mt * 8 + g * 4;
    out[((size_t)(m + 0) * BQ + b) * CC + c] = __logf(fmaxf(s0, 1e-5f) + 3e-5f);
    out[((size_t)(m + 1) * BQ + b) * CC + c] = __logf(fmaxf(s1, 1e-5f) + 3e-5f);
    out[((size_t)(m + 2) * BQ + b) * CC + c] = __logf(fmaxf(s2, 1e-5f) + 3e-5f);
    out[((size_t)(m + 3) * BQ + b) * CC + c] = __logf(fmaxf(s3, 1e-5f) + 3e-5f);
  }
}

extern "C" void kernel_launch(void* const* d_in, const int* in_sizes, int n_in,
                              void* d_out, int out_size, void* d_ws, size_t ws_size,
                              hipStream_t stream) {
  const float* train = (const float*)d_in[0];
  const float* test  = (const float*)d_in[1];
  const int*   tgt   = (const int*)d_in[2];
  const float* Wq    = (const float*)d_in[3];
  const float* bq    = (const float*)d_in[4];
  const float* Wk    = (const float*)d_in[5];
  const float* bk    = (const float*)d_in[6];
  float* out = (float*)d_out;

  char* ws = (char*)d_ws;
  bf16*  WqT  = (bf16*)(ws);                       //    393,216 B
  bf16*  WkT  = (bf16*)(ws + 393216);              //    393,216 B
  bf16*  Qb   = (bf16*)(ws + 786432);              //  6,291,456 B
  bf16*  Kb   = (bf16*)(ws + 7077888);             // 12,582,912 B
  float* Zp   = (float*)(ws + 19660800);           //  1,572,864 B
  bf16*  Wbuf = (bf16*)(ws + 21233664);            // 33,554,432 B
  int*   offs = (int*)(ws + 54788096);             //     16,416 B
  int*   idxs = (int*)(ws + 54804512);             //     65,536 B

  transw_kernel<<<48, 256, 0, stream>>>(Wq, WqT);
  transw_kernel<<<48, 256, 0, stream>>>(Wk, WkT);
  build_kernel<<<BQ, 512, 0, stream>>>(tgt, offs, idxs);
  proj_kernel<<<768, 256, 0, stream>>>(test, train, WqT, WkT, bq, bk, Qb, Kb);
  zpass_kernel<<<1024, 256, 0, stream>>>(Qb, Kb, Zp);
  wpass_kernel<<<1024, 256, 0, stream>>>(Qb, Kb, Zp, Wbuf);
  gather_kernel<<<1024, 512, 0, stream>>>(Wbuf, offs, idxs, out);
}

// Round 7
// 112.251 us; speedup vs baseline: 2.8531x; 1.0053x over previous
//
#include <hip/hip_runtime.h>
#include <hip/hip_bf16.h>

#define BQ 8      // batches
#define NN 2048   // train rows (keys)
#define MM 1024   // test rows (queries)
#define EE 512    // input size
#define NH 6      // heads
#define AA 384    // attn size (NH*64)
#define CC 512    // classes

#define KROW_B (AA * 2)          // 768 bytes per K row
#define TILE_B (16 * KROW_B)     // 12288 bytes per 16-row K tile
#define STILE_B (32 * KROW_B)    // 24576 bytes per 32-row super-tile
#define WROW_B (EE * 2)          // 1024 bytes per W row
#define WTILE_B (16 * WROW_B)    // 16384 bytes per 16-row W tile

// fold SDPA scale and log2(e) into Q so score passes use raw v_exp_f32 (exp2)
#define QSCALE 0.1803368801111204f   // 0.125 * log2(e)

typedef __bf16 bf16x8 __attribute__((ext_vector_type(8)));
typedef float  f32x4  __attribute__((ext_vector_type(4)));
using bf16 = __hip_bfloat16;

static __device__ __forceinline__ f32x4 mfma16(bf16x8 a, bf16x8 b, f32x4 c) {
  return __builtin_amdgcn_mfma_f32_16x16x32_bf16(a, b, c, 0, 0, 0);
}

typedef __attribute__((address_space(1))) const void gconst_void;
typedef __attribute__((address_space(3))) void lds_void_t;
static __device__ __forceinline__ void ld_lds16(const void* g, void* l) {
  __builtin_amdgcn_global_load_lds((gconst_void*)g, (lds_void_t*)l, 16, 0, 0);
}

static __device__ __forceinline__ unsigned short f2bfu(float x) {
  union { __hip_bfloat16 h; unsigned short u; } v;
  v.h = __float2bfloat16(x);
  return v.u;
}
static __device__ __forceinline__ float bf2f(unsigned short u) {
  union { unsigned int i; float f; } x;
  x.i = ((unsigned int)u) << 16;
  return x.f;
}

// ---------------- W[K][N] -> WT[N][K] bf16, LDS tile transpose ----------------
__global__ __launch_bounds__(256) void transw_kernel(const float* __restrict__ W, bf16* __restrict__ WT) {
  __shared__ float t[64][65];
  int kb = (blockIdx.x / 6) * 64, nb = (blockIdx.x % 6) * 64;
  int tid = threadIdx.x;
  int lr = tid >> 4, lc = (tid & 15) * 4;
  #pragma unroll
  for (int p = 0; p < 4; p++) {
    int k = lr + p * 16;
    float4 v = *reinterpret_cast<const float4*>(W + (size_t)(kb + k) * AA + nb + lc);
    t[k][lc] = v.x; t[k][lc + 1] = v.y; t[k][lc + 2] = v.z; t[k][lc + 3] = v.w;
  }
  __syncthreads();
  #pragma unroll
  for (int p = 0; p < 4; p++) {
    int n = lr + p * 16;
    bf16* dst = WT + (size_t)(nb + n) * EE + kb + lc;
    dst[0] = __float2bfloat16(t[lc][n]);
    dst[1] = __float2bfloat16(t[lc + 1][n]);
    dst[2] = __float2bfloat16(t[lc + 2][n]);
    dst[3] = __float2bfloat16(t[lc + 3][n]);
  }
}

// ---------------- CSR build ----------------
__global__ __launch_bounds__(512) void build_kernel(const int* __restrict__ targets,
                                                    int* __restrict__ offs, int* __restrict__ idxs) {
  __shared__ int cnt[CC], ssum[CC], pos[CC];
  int b = blockIdx.x, tid = threadIdx.x;
  cnt[tid] = 0;
  __syncthreads();
  int t[4];
  #pragma unroll
  for (int i = 0; i < 4; i++) {
    t[i] = targets[b * NN + tid * 4 + i];
    atomicAdd(&cnt[t[i]], 1);
  }
  __syncthreads();
  ssum[tid] = cnt[tid];
  __syncthreads();
  for (int d = 1; d < CC; d <<= 1) {
    int v = (tid >= d) ? ssum[tid - d] : 0;
    __syncthreads();
    ssum[tid] += v;
    __syncthreads();
  }
  int excl = ssum[tid] - cnt[tid];
  offs[b * (CC + 1) + tid] = excl;
  if (tid == CC - 1) offs[b * (CC + 1) + CC] = NN;
  pos[tid] = excl;
  __syncthreads();
  #pragma unroll
  for (int i = 0; i < 4; i++) {
    int p = atomicAdd(&pos[t[i]], 1);
    idxs[b * NN + p] = tid * 4 + i;
  }
}

// ---------------- projections (f32 in, bf16 out), 3-deep store-aware pipeline ----------------
__global__ __launch_bounds__(256, 3) void proj_kernel(
    const float* __restrict__ test, const float* __restrict__ train,
    const bf16* __restrict__ WqT, const bf16* __restrict__ WkT,
    const float* __restrict__ bq, const float* __restrict__ bk,
    bf16* __restrict__ Qb, bf16* __restrict__ Kb)
{
  __shared__ char wbuf[3][WTILE_B];   // 48 KB
  int tid = threadIdx.x, wid = tid >> 6, lane = tid & 63;
  int bid = blockIdx.x;
  int sub = bid & 1, unit = bid >> 1;
  const float* A; const bf16* WT; const float* bias; bf16* C; float scale; int m0;
  if (unit < 128) { A = test;  WT = WqT; bias = bq; C = Qb; scale = QSCALE; m0 = unit * 64; }
  else            { A = train; WT = WkT; bias = bk; C = Kb; scale = 1.0f;   m0 = (unit - 128) * 64; }
  m0 += wid * 16;
  int row = lane & 15, hi = lane >> 4;

  bf16x8 af[16];
  const float* arow = A + (size_t)(m0 + row) * EE + hi * 8;
  #pragma unroll
  for (int ks = 0; ks < 16; ks++) {
    float4 u = *reinterpret_cast<const float4*>(arow + ks * 32);
    float4 v = *reinterpret_cast<const float4*>(arow + ks * 32 + 4);
    bf16x8 f;
    f[0] = (__bf16)u.x; f[1] = (__bf16)u.y; f[2] = (__bf16)u.z; f[3] = (__bf16)u.w;
    f[4] = (__bf16)v.x; f[5] = (__bf16)v.y; f[6] = (__bf16)v.z; f[7] = (__bf16)v.w;
    af[ks] = f;
  }

  int ldso[4], srco[4];
  #pragma unroll
  for (int i = 0; i < 4; i++) {
    int off = tid * 16 + i * 4096;
    int rw = off >> 10, c = off & 1023;
    ldso[i] = off;
    srco[i] = rw * WROW_B + (c ^ ((rw & 7) << 4));
  }
  const char* wgbase = (const char*)WT + (size_t)sub * 12 * WTILE_B;
  int sw = (row & 7) << 4;

  auto stage = [&](int t, int buf) {
    const char* src = wgbase + (size_t)t * WTILE_B;
    #pragma unroll
    for (int i = 0; i < 4; i++) ld_lds16(src + srco[i], wbuf[buf] + ldso[i]);
  };
  auto compute = [&](int buf, int t) {
    const char* wb = wbuf[buf] + row * WROW_B;
    f32x4 acc0 = {0.f, 0.f, 0.f, 0.f}, acc1 = {0.f, 0.f, 0.f, 0.f};
    #pragma unroll
    for (int ks = 0; ks < 16; ks += 2) {
      bf16x8 w0 = *reinterpret_cast<const bf16x8*>(wb + ((hi * 16 + ks * 64) ^ sw));
      bf16x8 w1 = *reinterpret_cast<const bf16x8*>(wb + ((hi * 16 + (ks + 1) * 64) ^ sw));
      acc0 = mfma16(af[ks], w0, acc0);
      acc1 = mfma16(af[ks + 1], w1, acc1);
    }
    f32x4 acc = acc0 + acc1;
    int ocol = (sub * 12 + t) * 16 + row;
    float bv = bias[ocol];
    #pragma unroll
    for (int j = 0; j < 4; j++)
      C[(size_t)(m0 + hi * 4 + j) * AA + ocol] = __float2bfloat16((acc[j] + bv) * scale);
  };

  stage(0, 0);
  stage(1, 1);
  asm volatile("s_waitcnt vmcnt(4)" ::: "memory");
  __builtin_amdgcn_s_barrier();
  __builtin_amdgcn_sched_barrier(0);
  stage(2, 2);
  compute(0, 0);

  int cur = 1, stg = 0;
  #pragma unroll 1
  for (int t = 1; t < 11; t++) {
    asm volatile("s_waitcnt vmcnt(8)" ::: "memory");
    __builtin_amdgcn_s_barrier();
    __builtin_amdgcn_sched_barrier(0);
    if (t < 10) stage(t + 2, stg);
    compute(cur, t);
    cur = cur + 1 < 3 ? cur + 1 : 0;
    stg = stg + 1 < 3 ? stg + 1 : 0;
  }
  asm volatile("s_waitcnt vmcnt(4)" ::: "memory");
  __builtin_amdgcn_s_barrier();
  __builtin_amdgcn_sched_barrier(0);
  compute(cur, 11);
}

// ---------------- pass 1: Z partials. 32-row super-tiles, 2-buffer, 8 phases ----------------
// grid = 8b x 16mt(64m) x 8nc(256n) = 1024
__global__ __launch_bounds__(256, 3) void zpass_kernel(
    const bf16* __restrict__ Qb, const bf16* __restrict__ Kb, float* __restrict__ Zp)
{
  __shared__ char kbuf[2][STILE_B];    // 48 KB
  int id = blockIdx.x;
  int b = id & 7, r = id >> 3, mt = r & 15, nc = r >> 4;
  int tid = threadIdx.x, wid = tid >> 6, lane = tid & 63;
  int m0 = mt * 64 + wid * 16, n0 = nc * 256;
  int row = lane & 15, hi = lane >> 4;

  bf16x8 qf[12];
  const bf16* qrow = Qb + ((size_t)(b * MM + m0 + row)) * AA + hi * 8;
  #pragma unroll
  for (int ks = 0; ks < 12; ks++) qf[ks] = *reinterpret_cast<const bf16x8*>(qrow + ks * 32);

  // staging: 6 x 16B per thread over 24576 B; linear dest, inverse-swizzled source
  int ldso[6], srco[6];
  #pragma unroll
  for (int i = 0; i < 6; i++) {
    int off = tid * 16 + i * 4096;
    int rw = off / KROW_B, c = off - rw * KROW_B;
    ldso[i] = off;
    srco[i] = rw * KROW_B + (c ^ ((rw & 7) << 4));
  }
  const char* kgbase = (const char*)(Kb + ((size_t)(b * NN + n0)) * AA);

  int sw = (row & 7) << 4;
  int rbase = row * KROW_B;
  int x0 = rbase + ((hi * 16) ^ sw);
  int x1 = rbase + (((hi * 16) + 64) ^ sw);

  float zacc[NH][4];
  #pragma unroll
  for (int h = 0; h < NH; h++)
    #pragma unroll
    for (int j = 0; j < 4; j++) zacc[h][j] = 0.f;

  auto stage = [&](int t, int buf) {
    const char* src = kgbase + (size_t)t * STILE_B;
    #pragma unroll
    for (int i = 0; i < 6; i++) ld_lds16(src + srco[i], kbuf[buf] + ldso[i]);
  };
  auto compute = [&](int buf) {
    __builtin_amdgcn_s_setprio(1);
    #pragma unroll
    for (int s = 0; s < 2; s++) {
      const char* kb = kbuf[buf] + s * TILE_B;
      #pragma unroll
      for (int h = 0; h < NH; h++) {
        bf16x8 k0 = *reinterpret_cast<const bf16x8*>(kb + h * 128 + x0);
        bf16x8 k1 = *reinterpret_cast<const bf16x8*>(kb + h * 128 + x1);
        f32x4 acc = {0.f, 0.f, 0.f, 0.f};
        acc = mfma16(qf[2 * h], k0, acc);
        acc = mfma16(qf[2 * h + 1], k1, acc);
        #pragma unroll
        for (int j = 0; j < 4; j++) zacc[h][j] += __builtin_amdgcn_exp2f(acc[j]);
      }
    }
    __builtin_amdgcn_s_setprio(0);
  };

  stage(0, 0);
  asm volatile("s_waitcnt vmcnt(0)" ::: "memory");   // drain Q frags + tile 0
  __builtin_amdgcn_s_barrier();
  __builtin_amdgcn_sched_barrier(0);
  stage(1, 1);
  compute(0);

  #pragma unroll 1
  for (int i = 1; i < 8; i++) {
    asm volatile("s_waitcnt vmcnt(0)" ::: "memory"); // only L(i) outstanding (no stores)
    __builtin_amdgcn_s_barrier();
    __builtin_amdgcn_sched_barrier(0);
    if (i < 7) stage(i + 1, (i + 1) & 1);
    compute(i & 1);
  }

  #pragma unroll
  for (int h = 0; h < NH; h++)
    #pragma unroll
    for (int j = 0; j < 4; j++) {
      float v = zacc[h][j];
      v += __shfl_xor(v, 1); v += __shfl_xor(v, 2);
      v += __shfl_xor(v, 4); v += __shfl_xor(v, 8);
      zacc[h][j] = v;
    }
  if (row == 0) {
    #pragma unroll
    for (int h = 0; h < NH; h++)
      #pragma unroll
      for (int j = 0; j < 4; j++)
        Zp[(((size_t)nc * 8 + b) * NH + h) * MM + m0 + hi * 4 + j] = zacc[h][j];
  }
}

// ---------------- pass 2: weights W2[b][m/4][n][4] bf16, super-tile pipeline ----------------
__global__ __launch_bounds__(256, 3) void wpass_kernel(
    const bf16* __restrict__ Qb, const bf16* __restrict__ Kb,
    const float* __restrict__ Zp, bf16* __restrict__ W2)
{
  __shared__ char kbuf[2][STILE_B];    // 48 KB
  int id = blockIdx.x;
  int b = id & 7, r = id >> 3, mt = r & 15, nc = r >> 4;
  int tid = threadIdx.x, wid = tid >> 6, lane = tid & 63;
  int m0 = mt * 64 + wid * 16, n0 = nc * 256;
  int row = lane & 15, hi = lane >> 4;

  bf16x8 qf[12];
  const bf16* qrow = Qb + ((size_t)(b * MM + m0 + row)) * AA + hi * 8;
  #pragma unroll
  for (int ks = 0; ks < 12; ks++) qf[ks] = *reinterpret_cast<const bf16x8*>(qrow + ks * 32);

  float rz[NH][4];
  #pragma unroll
  for (int h = 0; h < NH; h++) {
    f32x4 z = {0.f, 0.f, 0.f, 0.f};
    #pragma unroll
    for (int p = 0; p < 8; p++)
      z += *reinterpret_cast<const f32x4*>(Zp + (((size_t)p * 8 + b) * NH + h) * MM + m0 + hi * 4);
    #pragma unroll
    for (int j = 0; j < 4; j++) rz[h][j] = 1.0f / (6.0f * z[j]);
  }

  int ldso[6], srco[6];
  #pragma unroll
  for (int i = 0; i < 6; i++) {
    int off = tid * 16 + i * 4096;
    int rw = off / KROW_B, c = off - rw * KROW_B;
    ldso[i] = off;
    srco[i] = rw * KROW_B + (c ^ ((rw & 7) << 4));
  }
  const char* kgbase = (const char*)(Kb + ((size_t)(b * NN + n0)) * AA);

  int sw = (row & 7) << 4;
  int rbase = row * KROW_B;
  int x0 = rbase + ((hi * 16) ^ sw);
  int x1 = rbase + (((hi * 16) + 64) ^ sw);

  int m4 = (m0 >> 2) + hi;

  auto stage = [&](int t, int buf) {
    const char* src = kgbase + (size_t)t * STILE_B;
    #pragma unroll
    for (int i = 0; i < 6; i++) ld_lds16(src + srco[i], kbuf[buf] + ldso[i]);
  };
  auto compute = [&](int buf, int st) {          // issues 2 x 8B stores
    #pragma unroll
    for (int s = 0; s < 2; s++) {
      const char* kb = kbuf[buf] + s * TILE_B;
      __builtin_amdgcn_s_setprio(1);
      float w0 = 0.f, w1 = 0.f, w2 = 0.f, w3 = 0.f;
      #pragma unroll
      for (int h = 0; h < NH; h++) {
        bf16x8 k0 = *reinterpret_cast<const bf16x8*>(kb + h * 128 + x0);
        bf16x8 k1 = *reinterpret_cast<const bf16x8*>(kb + h * 128 + x1);
        f32x4 acc = {0.f, 0.f, 0.f, 0.f};
        acc = mfma16(qf[2 * h], k0, acc);
        acc = mfma16(qf[2 * h + 1], k1, acc);
        w0 += __builtin_amdgcn_exp2f(acc[0]) * rz[h][0];
        w1 += __builtin_amdgcn_exp2f(acc[1]) * rz[h][1];
        w2 += __builtin_amdgcn_exp2f(acc[2]) * rz[h][2];
        w3 += __builtin_amdgcn_exp2f(acc[3]) * rz[h][3];
      }
      __builtin_amdgcn_s_setprio(0);
      int n = n0 + (st * 2 + s) * 16 + row;
      ushort4 q;
      q.x = f2bfu(w0); q.y = f2bfu(w1); q.z = f2bfu(w2); q.w = f2bfu(w3);
      *reinterpret_cast<ushort4*>((unsigned short*)W2 + (((size_t)(b * 256 + m4)) * NN + n) * 4) = q;
    }
  };

  stage(0, 0);
  asm volatile("s_waitcnt vmcnt(0)" ::: "memory");   // drain Q + rz + tile 0
  __builtin_amdgcn_s_barrier();
  __builtin_amdgcn_sched_barrier(0);
  stage(1, 1);
  compute(0, 0);

  #pragma unroll 1
  for (int i = 1; i < 8; i++) {
    // queue at this point: [L(i):6, S(i-1):2] -> retire L(i), keep stores
    asm volatile("s_waitcnt vmcnt(2)" ::: "memory");
    __builtin_amdgcn_s_barrier();
    __builtin_amdgcn_sched_barrier(0);
    if (i < 7) stage(i + 1, (i + 1) & 1);
    compute(i & 1, i);
  }
}

// ---------------- pass 3: CSR gather + log. grid = 8b x 128 m-chunks(8m) = 1024 ----------------
__global__ __launch_bounds__(512) void gather_kernel(
    const bf16* __restrict__ W2, const int* __restrict__ offs,
    const int* __restrict__ idxs, float* __restrict__ out)
{
  __shared__ char wl[2 * NN * 8];       // 32 KB
  __shared__ int ilb[NN];               // 8 KB
  int id = blockIdx.x;
  int b = id & 7, mt = id >> 3;
  int g0 = mt * 2;
  int tid = threadIdx.x;

  const uint4* src = (const uint4*)((const unsigned short*)W2 + ((size_t)(b * 256 + g0)) * NN * 4);
  uint4* dst = (uint4*)wl;
  #pragma unroll
  for (int i = tid; i < 2 * NN * 8 / 16; i += 512) dst[i] = src[i];
  const int* il = idxs + b * NN;
  #pragma unroll
  for (int i = tid; i < NN; i += 512) ilb[i] = il[i];
  __syncthreads();

  int c = tid;
  int o0 = offs[b * (CC + 1) + c], o1 = offs[b * (CC + 1) + c + 1];
  #pragma unroll 1
  for (int g = 0; g < 2; g++) {
    float s0 = 0.f, s1 = 0.f, s2 = 0.f, s3 = 0.f;
    for (int i = o0; i < o1; i++) {
      int idx = ilb[i];
      ushort4 v = *reinterpret_cast<const ushort4*>(wl + g * (NN * 8) + idx * 8);
      s0 += bf2f(v.x); s1 += bf2f(v.y); s2 += bf2f(v.z); s3 += bf2f(v.w);
    }
    int m = mt * 8 + g * 4;
    out[((size_t)(m + 0) * BQ + b) * CC + c] = __logf(fmaxf(s0, 1e-5f) + 3e-5f);
    out[((size_t)(m + 1) * BQ + b) * CC + c] = __logf(fmaxf(s1, 1e-5f) + 3e-5f);
    out[((size_t)(m + 2) * BQ + b) * CC + c] = __logf(fmaxf(s2, 1e-5f) + 3e-5f);
    out[((size_t)(m + 3) * BQ + b) * CC + c] = __logf(fmaxf(s3, 1e-5f) + 3e-5f);
  }
}

extern "C" void kernel_launch(void* const* d_in, const int* in_sizes, int n_in,
                              void* d_out, int out_size, void* d_ws, size_t ws_size,
                              hipStream_t stream) {
  const float* train = (const float*)d_in[0];
  const float* test  = (const float*)d_in[1];
  const int*   tgt   = (const int*)d_in[2];
  const float* Wq    = (const float*)d_in[3];
  const float* bq    = (const float*)d_in[4];
  const float* Wk    = (const float*)d_in[5];
  const float* bk    = (const float*)d_in[6];
  float* out = (float*)d_out;

  char* ws = (char*)d_ws;
  bf16*  WqT  = (bf16*)(ws);                       //    393,216 B
  bf16*  WkT  = (bf16*)(ws + 393216);              //    393,216 B
  bf16*  Qb   = (bf16*)(ws + 786432);              //  6,291,456 B
  bf16*  Kb   = (bf16*)(ws + 7077888);             // 12,582,912 B
  float* Zp   = (float*)(ws + 19660800);           //  1,572,864 B
  bf16*  Wbuf = (bf16*)(ws + 21233664);            // 33,554,432 B
  int*   offs = (int*)(ws + 54788096);             //     16,416 B
  int*   idxs = (int*)(ws + 54804512);             //     65,536 B

  transw_kernel<<<48, 256, 0, stream>>>(Wq, WqT);
  transw_kernel<<<48, 256, 0, stream>>>(Wk, WkT);
  build_kernel<<<BQ, 512, 0, stream>>>(tgt, offs, idxs);
  proj_kernel<<<768, 256, 0, stream>>>(test, train, WqT, WkT, bq, bk, Qb, Kb);
  zpass_kernel<<<1024, 256, 0, stream>>>(Qb, Kb, Zp);
  wpass_kernel<<<1024, 256, 0, stream>>>(Qb, Kb, Zp, Wbuf);
  gather_kernel<<<1024, 512, 0, stream>>>(Wbuf, offs, idxs, out);
}

// Round 8
// 108.403 us; speedup vs baseline: 2.9544x; 1.0355x over previous
//
#include <hip/hip_runtime.h>
#include <hip/hip_bf16.h>

#define BQ 8      // batches
#define NN 2048   // train rows (keys)
#define MM 1024   // test rows (queries)
#define EE 512    // input size
#define NH 6      // heads
#define AA 384    // attn size (NH*64)
#define CC 512    // classes

#define KROW_B (AA * 2)          // 768 bytes per K row
#define TILE_B (16 * KROW_B)     // 12288 bytes per 16-row K tile
#define STILE_B (32 * KROW_B)    // 24576 bytes per 32-row super-tile
#define WROW_B (EE * 2)          // 1024 bytes per W row
#define WTILE_B (16 * WROW_B)    // 16384 bytes per 16-row W tile

// fold SDPA scale and log2(e) into Q so score passes use raw v_exp_f32 (exp2)
#define QSCALE 0.1803368801111204f   // 0.125 * log2(e)

typedef __bf16 bf16x8 __attribute__((ext_vector_type(8)));
typedef float  f32x4  __attribute__((ext_vector_type(4)));
using bf16 = __hip_bfloat16;

static __device__ __forceinline__ f32x4 mfma16(bf16x8 a, bf16x8 b, f32x4 c) {
  return __builtin_amdgcn_mfma_f32_16x16x32_bf16(a, b, c, 0, 0, 0);
}

typedef __attribute__((address_space(1))) const void gconst_void;
typedef __attribute__((address_space(3))) void lds_void_t;
static __device__ __forceinline__ void ld_lds16(const void* g, void* l) {
  __builtin_amdgcn_global_load_lds((gconst_void*)g, (lds_void_t*)l, 16, 0, 0);
}

static __device__ __forceinline__ unsigned short f2bfu(float x) {
  union { __hip_bfloat16 h; unsigned short u; } v;
  v.h = __float2bfloat16(x);
  return v.u;
}
static __device__ __forceinline__ float bf2f(unsigned short u) {
  union { unsigned int i; float f; } x;
  x.i = ((unsigned int)u) << 16;
  return x.f;
}

// ---------------- W[K][N] -> WT[N][K] bf16, both weights in one launch ----------------
__global__ __launch_bounds__(256) void transw_kernel(
    const float* __restrict__ Wq, const float* __restrict__ Wk,
    bf16* __restrict__ WqT, bf16* __restrict__ WkT) {
  __shared__ float t[64][65];
  int id = blockIdx.x;
  const float* W = (id < 48) ? Wq : Wk;
  bf16* WT = (id < 48) ? WqT : WkT;
  if (id >= 48) id -= 48;
  int kb = (id / 6) * 64, nb = (id % 6) * 64;
  int tid = threadIdx.x;
  int lr = tid >> 4, lc = (tid & 15) * 4;
  #pragma unroll
  for (int p = 0; p < 4; p++) {
    int k = lr + p * 16;
    float4 v = *reinterpret_cast<const float4*>(W + (size_t)(kb + k) * AA + nb + lc);
    t[k][lc] = v.x; t[k][lc + 1] = v.y; t[k][lc + 2] = v.z; t[k][lc + 3] = v.w;
  }
  __syncthreads();
  #pragma unroll
  for (int p = 0; p < 4; p++) {
    int n = lr + p * 16;
    bf16* dst = WT + (size_t)(nb + n) * EE + kb + lc;
    dst[0] = __float2bfloat16(t[lc][n]);
    dst[1] = __float2bfloat16(t[lc + 1][n]);
    dst[2] = __float2bfloat16(t[lc + 2][n]);
    dst[3] = __float2bfloat16(t[lc + 3][n]);
  }
}

// ---------------- CSR build ----------------
__global__ __launch_bounds__(512) void build_kernel(const int* __restrict__ targets,
                                                    int* __restrict__ offs, int* __restrict__ idxs) {
  __shared__ int cnt[CC], ssum[CC], pos[CC];
  int b = blockIdx.x, tid = threadIdx.x;
  cnt[tid] = 0;
  __syncthreads();
  int t[4];
  #pragma unroll
  for (int i = 0; i < 4; i++) {
    t[i] = targets[b * NN + tid * 4 + i];
    atomicAdd(&cnt[t[i]], 1);
  }
  __syncthreads();
  ssum[tid] = cnt[tid];
  __syncthreads();
  for (int d = 1; d < CC; d <<= 1) {
    int v = (tid >= d) ? ssum[tid - d] : 0;
    __syncthreads();
    ssum[tid] += v;
    __syncthreads();
  }
  int excl = ssum[tid] - cnt[tid];
  offs[b * (CC + 1) + tid] = excl;
  if (tid == CC - 1) offs[b * (CC + 1) + CC] = NN;
  pos[tid] = excl;
  __syncthreads();
  #pragma unroll
  for (int i = 0; i < 4; i++) {
    int p = atomicAdd(&pos[t[i]], 1);
    idxs[b * NN + p] = tid * 4 + i;
  }
}

// ---------------- projections (f32 in, bf16 out), 3-deep store-aware pipeline ----------------
__global__ __launch_bounds__(256, 3) void proj_kernel(
    const float* __restrict__ test, const float* __restrict__ train,
    const bf16* __restrict__ WqT, const bf16* __restrict__ WkT,
    const float* __restrict__ bq, const float* __restrict__ bk,
    bf16* __restrict__ Qb, bf16* __restrict__ Kb)
{
  __shared__ char wbuf[3][WTILE_B];   // 48 KB
  int tid = threadIdx.x, wid = tid >> 6, lane = tid & 63;
  int bid = blockIdx.x;
  int sub = bid & 1, unit = bid >> 1;
  const float* A; const bf16* WT; const float* bias; bf16* C; float scale; int m0;
  if (unit < 128) { A = test;  WT = WqT; bias = bq; C = Qb; scale = QSCALE; m0 = unit * 64; }
  else            { A = train; WT = WkT; bias = bk; C = Kb; scale = 1.0f;   m0 = (unit - 128) * 64; }
  m0 += wid * 16;
  int row = lane & 15, hi = lane >> 4;

  bf16x8 af[16];
  const float* arow = A + (size_t)(m0 + row) * EE + hi * 8;
  #pragma unroll
  for (int ks = 0; ks < 16; ks++) {
    float4 u = *reinterpret_cast<const float4*>(arow + ks * 32);
    float4 v = *reinterpret_cast<const float4*>(arow + ks * 32 + 4);
    bf16x8 f;
    f[0] = (__bf16)u.x; f[1] = (__bf16)u.y; f[2] = (__bf16)u.z; f[3] = (__bf16)u.w;
    f[4] = (__bf16)v.x; f[5] = (__bf16)v.y; f[6] = (__bf16)v.z; f[7] = (__bf16)v.w;
    af[ks] = f;
  }

  int ldso[4], srco[4];
  #pragma unroll
  for (int i = 0; i < 4; i++) {
    int off = tid * 16 + i * 4096;
    int rw = off >> 10, c = off & 1023;
    ldso[i] = off;
    srco[i] = rw * WROW_B + (c ^ ((rw & 7) << 4));
  }
  const char* wgbase = (const char*)WT + (size_t)sub * 12 * WTILE_B;
  int sw = (row & 7) << 4;

  auto stage = [&](int t, int buf) {
    const char* src = wgbase + (size_t)t * WTILE_B;
    #pragma unroll
    for (int i = 0; i < 4; i++) ld_lds16(src + srco[i], wbuf[buf] + ldso[i]);
  };
  auto compute = [&](int buf, int t) {
    const char* wb = wbuf[buf] + row * WROW_B;
    f32x4 acc0 = {0.f, 0.f, 0.f, 0.f}, acc1 = {0.f, 0.f, 0.f, 0.f};
    #pragma unroll
    for (int ks = 0; ks < 16; ks += 2) {
      bf16x8 w0 = *reinterpret_cast<const bf16x8*>(wb + ((hi * 16 + ks * 64) ^ sw));
      bf16x8 w1 = *reinterpret_cast<const bf16x8*>(wb + ((hi * 16 + (ks + 1) * 64) ^ sw));
      acc0 = mfma16(af[ks], w0, acc0);
      acc1 = mfma16(af[ks + 1], w1, acc1);
    }
    f32x4 acc = acc0 + acc1;
    int ocol = (sub * 12 + t) * 16 + row;
    float bv = bias[ocol];
    #pragma unroll
    for (int j = 0; j < 4; j++)
      C[(size_t)(m0 + hi * 4 + j) * AA + ocol] = __float2bfloat16((acc[j] + bv) * scale);
  };

  stage(0, 0);
  stage(1, 1);
  asm volatile("s_waitcnt vmcnt(4)" ::: "memory");
  __builtin_amdgcn_s_barrier();
  __builtin_amdgcn_sched_barrier(0);
  stage(2, 2);
  compute(0, 0);

  int cur = 1, stg = 0;
  #pragma unroll 1
  for (int t = 1; t < 11; t++) {
    asm volatile("s_waitcnt vmcnt(8)" ::: "memory");
    __builtin_amdgcn_s_barrier();
    __builtin_amdgcn_sched_barrier(0);
    if (t < 10) stage(t + 2, stg);
    compute(cur, t);
    cur = cur + 1 < 3 ? cur + 1 : 0;
    stg = stg + 1 < 3 ? stg + 1 : 0;
  }
  asm volatile("s_waitcnt vmcnt(4)" ::: "memory");
  __builtin_amdgcn_s_barrier();
  __builtin_amdgcn_sched_barrier(0);
  compute(cur, 11);
}

// ---------------- pass 1: Z partials. 32 m-rows/wave, K-frag shared by 2 m-sets ----------------
// grid = 8b x 8mt(128m) x 8nc(256n) = 512
__global__ __launch_bounds__(256, 2) void zpass_kernel(
    const bf16* __restrict__ Qb, const bf16* __restrict__ Kb, float* __restrict__ Zp)
{
  __shared__ char kbuf[2][STILE_B];    // 48 KB
  int id = blockIdx.x;
  int b = id & 7, r = id >> 3, mt = r & 7, nc = r >> 3;
  int tid = threadIdx.x, wid = tid >> 6, lane = tid & 63;
  int m0 = mt * 128 + wid * 32, n0 = nc * 256;
  int row = lane & 15, hi = lane >> 4;

  bf16x8 qf[2][12];
  #pragma unroll
  for (int s = 0; s < 2; s++) {
    const bf16* qrow = Qb + ((size_t)(b * MM + m0 + s * 16 + row)) * AA + hi * 8;
    #pragma unroll
    for (int ks = 0; ks < 12; ks++) qf[s][ks] = *reinterpret_cast<const bf16x8*>(qrow + ks * 32);
  }

  int ldso[6], srco[6];
  #pragma unroll
  for (int i = 0; i < 6; i++) {
    int off = tid * 16 + i * 4096;
    int rw = off / KROW_B, c = off - rw * KROW_B;
    ldso[i] = off;
    srco[i] = rw * KROW_B + (c ^ ((rw & 7) << 4));
  }
  const char* kgbase = (const char*)(Kb + ((size_t)(b * NN + n0)) * AA);

  int sw = (row & 7) << 4;
  int rbase = row * KROW_B;
  int x0 = rbase + ((hi * 16) ^ sw);
  int x1 = rbase + (((hi * 16) + 64) ^ sw);

  float zacc[2][NH][4];
  #pragma unroll
  for (int s = 0; s < 2; s++)
    #pragma unroll
    for (int h = 0; h < NH; h++)
      #pragma unroll
      for (int j = 0; j < 4; j++) zacc[s][h][j] = 0.f;

  auto stage = [&](int t, int buf) {
    const char* src = kgbase + (size_t)t * STILE_B;
    #pragma unroll
    for (int i = 0; i < 6; i++) ld_lds16(src + srco[i], kbuf[buf] + ldso[i]);
  };
  auto compute = [&](int buf) {
    __builtin_amdgcn_s_setprio(1);
    #pragma unroll
    for (int sub = 0; sub < 2; sub++) {
      const char* kb = kbuf[buf] + sub * TILE_B;
      #pragma unroll
      for (int h = 0; h < NH; h++) {
        bf16x8 k0 = *reinterpret_cast<const bf16x8*>(kb + h * 128 + x0);
        bf16x8 k1 = *reinterpret_cast<const bf16x8*>(kb + h * 128 + x1);
        f32x4 a0 = {0.f, 0.f, 0.f, 0.f}, a1 = {0.f, 0.f, 0.f, 0.f};
        a0 = mfma16(qf[0][2 * h], k0, a0);
        a1 = mfma16(qf[1][2 * h], k0, a1);
        a0 = mfma16(qf[0][2 * h + 1], k1, a0);
        a1 = mfma16(qf[1][2 * h + 1], k1, a1);
        #pragma unroll
        for (int j = 0; j < 4; j++) {
          zacc[0][h][j] += __builtin_amdgcn_exp2f(a0[j]);
          zacc[1][h][j] += __builtin_amdgcn_exp2f(a1[j]);
        }
      }
    }
    __builtin_amdgcn_s_setprio(0);
  };

  stage(0, 0);
  asm volatile("s_waitcnt vmcnt(0)" ::: "memory");   // drain Q frags + tile 0
  __builtin_amdgcn_s_barrier();
  __builtin_amdgcn_sched_barrier(0);
  stage(1, 1);
  compute(0);

  #pragma unroll 1
  for (int i = 1; i < 8; i++) {
    asm volatile("s_waitcnt vmcnt(0)" ::: "memory"); // only L(i) outstanding (no stores)
    __builtin_amdgcn_s_barrier();
    __builtin_amdgcn_sched_barrier(0);
    if (i < 7) stage(i + 1, (i + 1) & 1);
    compute(i & 1);
  }

  #pragma unroll
  for (int s = 0; s < 2; s++)
    #pragma unroll
    for (int h = 0; h < NH; h++)
      #pragma unroll
      for (int j = 0; j < 4; j++) {
        float v = zacc[s][h][j];
        v += __shfl_xor(v, 1); v += __shfl_xor(v, 2);
        v += __shfl_xor(v, 4); v += __shfl_xor(v, 8);
        zacc[s][h][j] = v;
      }
  if (row == 0) {
    #pragma unroll
    for (int s = 0; s < 2; s++)
      #pragma unroll
      for (int h = 0; h < NH; h++)
        #pragma unroll
        for (int j = 0; j < 4; j++)
          Zp[(((size_t)nc * 8 + b) * NH + h) * MM + m0 + s * 16 + hi * 4 + j] = zacc[s][h][j];
  }
}

// ---------------- pass 2: weights W2[b][m/4][n][4] bf16, 32 m-rows/wave ----------------
// grid = 512
__global__ __launch_bounds__(256, 2) void wpass_kernel(
    const bf16* __restrict__ Qb, const bf16* __restrict__ Kb,
    const float* __restrict__ Zp, bf16* __restrict__ W2)
{
  __shared__ char kbuf[2][STILE_B];    // 48 KB
  int id = blockIdx.x;
  int b = id & 7, r = id >> 3, mt = r & 7, nc = r >> 3;
  int tid = threadIdx.x, wid = tid >> 6, lane = tid & 63;
  int m0 = mt * 128 + wid * 32, n0 = nc * 256;
  int row = lane & 15, hi = lane >> 4;

  bf16x8 qf[2][12];
  #pragma unroll
  for (int s = 0; s < 2; s++) {
    const bf16* qrow = Qb + ((size_t)(b * MM + m0 + s * 16 + row)) * AA + hi * 8;
    #pragma unroll
    for (int ks = 0; ks < 12; ks++) qf[s][ks] = *reinterpret_cast<const bf16x8*>(qrow + ks * 32);
  }

  float rz[2][NH][4];
  #pragma unroll
  for (int s = 0; s < 2; s++)
    #pragma unroll
    for (int h = 0; h < NH; h++) {
      f32x4 z = {0.f, 0.f, 0.f, 0.f};
      #pragma unroll
      for (int p = 0; p < 8; p++)
        z += *reinterpret_cast<const f32x4*>(Zp + (((size_t)p * 8 + b) * NH + h) * MM + m0 + s * 16 + hi * 4);
      #pragma unroll
      for (int j = 0; j < 4; j++) rz[s][h][j] = 1.0f / (6.0f * z[j]);
    }

  int ldso[6], srco[6];
  #pragma unroll
  for (int i = 0; i < 6; i++) {
    int off = tid * 16 + i * 4096;
    int rw = off / KROW_B, c = off - rw * KROW_B;
    ldso[i] = off;
    srco[i] = rw * KROW_B + (c ^ ((rw & 7) << 4));
  }
  const char* kgbase = (const char*)(Kb + ((size_t)(b * NN + n0)) * AA);

  int sw = (row & 7) << 4;
  int rbase = row * KROW_B;
  int x0 = rbase + ((hi * 16) ^ sw);
  int x1 = rbase + (((hi * 16) + 64) ^ sw);

  int m4a = (m0 >> 2) + hi;           // set 0 group
  int m4b = ((m0 + 16) >> 2) + hi;    // set 1 group

  auto stage = [&](int t, int buf) {
    const char* src = kgbase + (size_t)t * STILE_B;
    #pragma unroll
    for (int i = 0; i < 6; i++) ld_lds16(src + srco[i], kbuf[buf] + ldso[i]);
  };
  auto compute = [&](int buf, int st) {          // issues 4 x 8B stores
    #pragma unroll
    for (int sub = 0; sub < 2; sub++) {
      const char* kb = kbuf[buf] + sub * TILE_B;
      __builtin_amdgcn_s_setprio(1);
      float w0a = 0.f, w1a = 0.f, w2a = 0.f, w3a = 0.f;
      float w0b = 0.f, w1b = 0.f, w2b = 0.f, w3b = 0.f;
      #pragma unroll
      for (int h = 0; h < NH; h++) {
        bf16x8 k0 = *reinterpret_cast<const bf16x8*>(kb + h * 128 + x0);
        bf16x8 k1 = *reinterpret_cast<const bf16x8*>(kb + h * 128 + x1);
        f32x4 a0 = {0.f, 0.f, 0.f, 0.f}, a1 = {0.f, 0.f, 0.f, 0.f};
        a0 = mfma16(qf[0][2 * h], k0, a0);
        a1 = mfma16(qf[1][2 * h], k0, a1);
        a0 = mfma16(qf[0][2 * h + 1], k1, a0);
        a1 = mfma16(qf[1][2 * h + 1], k1, a1);
        w0a += __builtin_amdgcn_exp2f(a0[0]) * rz[0][h][0];
        w1a += __builtin_amdgcn_exp2f(a0[1]) * rz[0][h][1];
        w2a += __builtin_amdgcn_exp2f(a0[2]) * rz[0][h][2];
        w3a += __builtin_amdgcn_exp2f(a0[3]) * rz[0][h][3];
        w0b += __builtin_amdgcn_exp2f(a1[0]) * rz[1][h][0];
        w1b += __builtin_amdgcn_exp2f(a1[1]) * rz[1][h][1];
        w2b += __builtin_amdgcn_exp2f(a1[2]) * rz[1][h][2];
        w3b += __builtin_amdgcn_exp2f(a1[3]) * rz[1][h][3];
      }
      __builtin_amdgcn_s_setprio(0);
      int n = n0 + (st * 2 + sub) * 16 + row;
      ushort4 qa, qb2;
      qa.x = f2bfu(w0a); qa.y = f2bfu(w1a); qa.z = f2bfu(w2a); qa.w = f2bfu(w3a);
      qb2.x = f2bfu(w0b); qb2.y = f2bfu(w1b); qb2.z = f2bfu(w2b); qb2.w = f2bfu(w3b);
      *reinterpret_cast<ushort4*>((unsigned short*)W2 + (((size_t)(b * 256 + m4a)) * NN + n) * 4) = qa;
      *reinterpret_cast<ushort4*>((unsigned short*)W2 + (((size_t)(b * 256 + m4b)) * NN + n) * 4) = qb2;
    }
  };

  stage(0, 0);
  asm volatile("s_waitcnt vmcnt(0)" ::: "memory");   // drain Q + rz + tile 0
  __builtin_amdgcn_s_barrier();
  __builtin_amdgcn_sched_barrier(0);
  stage(1, 1);
  compute(0, 0);

  #pragma unroll 1
  for (int i = 1; i < 8; i++) {
    // queue: [S(i-2):<=4, L(i):6, S(i-1):4] -> vmcnt(4) retires through L(i)
    asm volatile("s_waitcnt vmcnt(4)" ::: "memory");
    __builtin_amdgcn_s_barrier();
    __builtin_amdgcn_sched_barrier(0);
    if (i < 7) stage(i + 1, (i + 1) & 1);
    compute(i & 1, i);
  }
}

// ---------------- pass 3: CSR gather + log. grid = 8b x 128 m-chunks(8m) = 1024 ----------------
__global__ __launch_bounds__(512) void gather_kernel(
    const bf16* __restrict__ W2, const int* __restrict__ offs,
    const int* __restrict__ idxs, float* __restrict__ out)
{
  __shared__ char wl[2 * NN * 8];       // 32 KB
  __shared__ int ilb[NN];               // 8 KB
  int id = blockIdx.x;
  int b = id & 7, mt = id >> 3;
  int g0 = mt * 2;
  int tid = threadIdx.x;

  const uint4* src = (const uint4*)((const unsigned short*)W2 + ((size_t)(b * 256 + g0)) * NN * 4);
  uint4* dst = (uint4*)wl;
  #pragma unroll
  for (int i = tid; i < 2 * NN * 8 / 16; i += 512) dst[i] = src[i];
  const int* il = idxs + b * NN;
  #pragma unroll
  for (int i = tid; i < NN; i += 512) ilb[i] = il[i];
  __syncthreads();

  int c = tid;
  int o0 = offs[b * (CC + 1) + c], o1 = offs[b * (CC + 1) + c + 1];
  #pragma unroll 1
  for (int g = 0; g < 2; g++) {
    float s0 = 0.f, s1 = 0.f, s2 = 0.f, s3 = 0.f;
    for (int i = o0; i < o1; i++) {
      int idx = ilb[i];
      ushort4 v = *reinterpret_cast<const ushort4*>(wl + g * (NN * 8) + idx * 8);
      s0 += bf2f(v.x); s1 += bf2f(v.y); s2 += bf2f(v.z); s3 += bf2f(v.w);
    }
    int m = mt * 8 + g * 4;
    out[((size_t)(m + 0) * BQ + b) * CC + c] = __logf(fmaxf(s0, 1e-5f) + 3e-5f);
    out[((size_t)(m + 1) * BQ + b) * CC + c] = __logf(fmaxf(s1, 1e-5f) + 3e-5f);
    out[((size_t)(m + 2) * BQ + b) * CC + c] = __logf(fmaxf(s2, 1e-5f) + 3e-5f);
    out[((size_t)(m + 3) * BQ + b) * CC + c] = __logf(fmaxf(s3, 1e-5f) + 3e-5f);
  }
}

extern "C" void kernel_launch(void* const* d_in, const int* in_sizes, int n_in,
                              void* d_out, int out_size, void* d_ws, size_t ws_size,
                              hipStream_t stream) {
  const float* train = (const float*)d_in[0];
  const float* test  = (const float*)d_in[1];
  const int*   tgt   = (const int*)d_in[2];
  const float* Wq    = (const float*)d_in[3];
  const float* bq    = (const float*)d_in[4];
  const float* Wk    = (const float*)d_in[5];
  const float* bk    = (const float*)d_in[6];
  float* out = (float*)d_out;

  char* ws = (char*)d_ws;
  bf16*  WqT  = (bf16*)(ws);                       //    393,216 B
  bf16*  WkT  = (bf16*)(ws + 393216);              //    393,216 B
  bf16*  Qb   = (bf16*)(ws + 786432);              //  6,291,456 B
  bf16*  Kb   = (bf16*)(ws + 7077888);             // 12,582,912 B
  float* Zp   = (float*)(ws + 19660800);           //  1,572,864 B
  bf16*  Wbuf = (bf16*)(ws + 21233664);            // 33,554,432 B
  int*   offs = (int*)(ws + 54788096);             //     16,416 B
  int*   idxs = (int*)(ws + 54804512);             //     65,536 B

  transw_kernel<<<96, 256, 0, stream>>>(Wq, Wk, WqT, WkT);
  build_kernel<<<BQ, 512, 0, stream>>>(tgt, offs, idxs);
  proj_kernel<<<768, 256, 0, stream>>>(test, train, WqT, WkT, bq, bk, Qb, Kb);
  zpass_kernel<<<512, 256, 0, stream>>>(Qb, Kb, Zp);
  wpass_kernel<<<512, 256, 0, stream>>>(Qb, Kb, Zp, Wbuf);
  gather_kernel<<<1024, 512, 0, stream>>>(Wbuf, offs, idxs, out);
}

// Round 9
// 107.272 us; speedup vs baseline: 2.9856x; 1.0105x over previous
//
#include <hip/hip_runtime.h>
#include <hip/hip_bf16.h>

#define BQ 8      // batches
#define NN 2048   // train rows (keys)
#define MM 1024   // test rows (queries)
#define EE 512    // input size
#define NH 6      // heads
#define AA 384    // attn size (NH*64)
#define CC 512    // classes

#define KROW_B (AA * 2)          // 768 bytes per K row
#define TILE_B (16 * KROW_B)     // 12288 bytes per 16-row K tile
#define STILE_B (32 * KROW_B)    // 24576 bytes per 32-row super-tile
#define WROW_B (EE * 2)          // 1024 bytes per W row
#define WTILE_B (16 * WROW_B)    // 16384 bytes per 16-row W tile

// fold SDPA scale and log2(e) into Q so score passes use raw v_exp_f32 (exp2)
#define QSCALE 0.1803368801111204f   // 0.125 * log2(e)

typedef __bf16 bf16x8 __attribute__((ext_vector_type(8)));
typedef float  f32x4  __attribute__((ext_vector_type(4)));
using bf16 = __hip_bfloat16;

static __device__ __forceinline__ f32x4 mfma16(bf16x8 a, bf16x8 b, f32x4 c) {
  return __builtin_amdgcn_mfma_f32_16x16x32_bf16(a, b, c, 0, 0, 0);
}

typedef __attribute__((address_space(1))) const void gconst_void;
typedef __attribute__((address_space(3))) void lds_void_t;
static __device__ __forceinline__ void ld_lds16(const void* g, void* l) {
  __builtin_amdgcn_global_load_lds((gconst_void*)g, (lds_void_t*)l, 16, 0, 0);
}

static __device__ __forceinline__ unsigned short f2bfu(float x) {
  union { __hip_bfloat16 h; unsigned short u; } v;
  v.h = __float2bfloat16(x);
  return v.u;
}
static __device__ __forceinline__ float bf2f(unsigned short u) {
  union { unsigned int i; float f; } x;
  x.i = ((unsigned int)u) << 16;
  return x.f;
}

// ---------------- prep: W transposes (blocks 0..95) + padded-CSR build (96..103) ----------------
__global__ __launch_bounds__(512) void prep_kernel(
    const float* __restrict__ Wq, const float* __restrict__ Wk,
    bf16* __restrict__ WqT, bf16* __restrict__ WkT,
    const int* __restrict__ targets, int* __restrict__ cnts, int* __restrict__ idxP)
{
  __shared__ float t[64][65];
  __shared__ int cnt[CC], pos[CC];
  int bid = blockIdx.x, tid = threadIdx.x;
  if (bid < 96) {                        // transpose: 256 threads active
    if (tid >= 256) { __syncthreads(); return; }
    int id = bid;
    const float* W = (id < 48) ? Wq : Wk;
    bf16* WT = (id < 48) ? WqT : WkT;
    if (id >= 48) id -= 48;
    int kb = (id / 6) * 64, nb = (id % 6) * 64;
    int lr = tid >> 4, lc = (tid & 15) * 4;
    #pragma unroll
    for (int p = 0; p < 4; p++) {
      int k = lr + p * 16;
      float4 v = *reinterpret_cast<const float4*>(W + (size_t)(kb + k) * AA + nb + lc);
      t[k][lc] = v.x; t[k][lc + 1] = v.y; t[k][lc + 2] = v.z; t[k][lc + 3] = v.w;
    }
    __syncthreads();
    #pragma unroll
    for (int p = 0; p < 4; p++) {
      int n = lr + p * 16;
      bf16* dst = WT + (size_t)(nb + n) * EE + kb + lc;
      dst[0] = __float2bfloat16(t[lc][n]);
      dst[1] = __float2bfloat16(t[lc + 1][n]);
      dst[2] = __float2bfloat16(t[lc + 2][n]);
      dst[3] = __float2bfloat16(t[lc + 3][n]);
    }
    return;
  }
  // ---- build ----
  int b = bid - 96;
  cnt[tid] = 0;
  pos[tid] = 0;
  // sentinel-fill this class's 32-slot row
  int4 sent = make_int4(NN, NN, NN, NN);
  int4* prow = reinterpret_cast<int4*>(idxP + ((size_t)b * CC + tid) * 32);
  #pragma unroll
  for (int i = 0; i < 8; i++) prow[i] = sent;
  __syncthreads();
  int tv[4];
  #pragma unroll
  for (int i = 0; i < 4; i++) {
    tv[i] = targets[b * NN + tid * 4 + i];
    atomicAdd(&cnt[tv[i]], 1);
  }
  __syncthreads();
  cnts[b * CC + tid] = cnt[tid];
  __syncthreads();
  #pragma unroll
  for (int i = 0; i < 4; i++) {
    int p = atomicAdd(&pos[tv[i]], 1);
    if (p < 32) idxP[((size_t)b * CC + tv[i]) * 32 + p] = tid * 4 + i;
  }
}

// ---------------- projections (f32 in, bf16 out), 3-deep store-aware pipeline ----------------
__global__ __launch_bounds__(256, 3) void proj_kernel(
    const float* __restrict__ test, const float* __restrict__ train,
    const bf16* __restrict__ WqT, const bf16* __restrict__ WkT,
    const float* __restrict__ bq, const float* __restrict__ bk,
    bf16* __restrict__ Qb, bf16* __restrict__ Kb)
{
  __shared__ char wbuf[3][WTILE_B];   // 48 KB
  int tid = threadIdx.x, wid = tid >> 6, lane = tid & 63;
  int bid = blockIdx.x;
  int sub = bid & 1, unit = bid >> 1;
  const float* A; const bf16* WT; const float* bias; bf16* C; float scale; int m0;
  if (unit < 128) { A = test;  WT = WqT; bias = bq; C = Qb; scale = QSCALE; m0 = unit * 64; }
  else            { A = train; WT = WkT; bias = bk; C = Kb; scale = 1.0f;   m0 = (unit - 128) * 64; }
  m0 += wid * 16;
  int row = lane & 15, hi = lane >> 4;

  bf16x8 af[16];
  const float* arow = A + (size_t)(m0 + row) * EE + hi * 8;
  #pragma unroll
  for (int ks = 0; ks < 16; ks++) {
    float4 u = *reinterpret_cast<const float4*>(arow + ks * 32);
    float4 v = *reinterpret_cast<const float4*>(arow + ks * 32 + 4);
    bf16x8 f;
    f[0] = (__bf16)u.x; f[1] = (__bf16)u.y; f[2] = (__bf16)u.z; f[3] = (__bf16)u.w;
    f[4] = (__bf16)v.x; f[5] = (__bf16)v.y; f[6] = (__bf16)v.z; f[7] = (__bf16)v.w;
    af[ks] = f;
  }

  int ldso[4], srco[4];
  #pragma unroll
  for (int i = 0; i < 4; i++) {
    int off = tid * 16 + i * 4096;
    int rw = off >> 10, c = off & 1023;
    ldso[i] = off;
    srco[i] = rw * WROW_B + (c ^ ((rw & 7) << 4));
  }
  const char* wgbase = (const char*)WT + (size_t)sub * 12 * WTILE_B;
  int sw = (row & 7) << 4;

  auto stage = [&](int t, int buf) {
    const char* src = wgbase + (size_t)t * WTILE_B;
    #pragma unroll
    for (int i = 0; i < 4; i++) ld_lds16(src + srco[i], wbuf[buf] + ldso[i]);
  };
  auto compute = [&](int buf, int t) {
    const char* wb = wbuf[buf] + row * WROW_B;
    f32x4 acc0 = {0.f, 0.f, 0.f, 0.f}, acc1 = {0.f, 0.f, 0.f, 0.f};
    #pragma unroll
    for (int ks = 0; ks < 16; ks += 2) {
      bf16x8 w0 = *reinterpret_cast<const bf16x8*>(wb + ((hi * 16 + ks * 64) ^ sw));
      bf16x8 w1 = *reinterpret_cast<const bf16x8*>(wb + ((hi * 16 + (ks + 1) * 64) ^ sw));
      acc0 = mfma16(af[ks], w0, acc0);
      acc1 = mfma16(af[ks + 1], w1, acc1);
    }
    f32x4 acc = acc0 + acc1;
    int ocol = (sub * 12 + t) * 16 + row;
    float bv = bias[ocol];
    #pragma unroll
    for (int j = 0; j < 4; j++)
      C[(size_t)(m0 + hi * 4 + j) * AA + ocol] = __float2bfloat16((acc[j] + bv) * scale);
  };

  stage(0, 0);
  stage(1, 1);
  asm volatile("s_waitcnt vmcnt(4)" ::: "memory");
  __builtin_amdgcn_s_barrier();
  __builtin_amdgcn_sched_barrier(0);
  stage(2, 2);
  compute(0, 0);

  int cur = 1, stg = 0;
  #pragma unroll 1
  for (int t = 1; t < 11; t++) {
    asm volatile("s_waitcnt vmcnt(8)" ::: "memory");
    __builtin_amdgcn_s_barrier();
    __builtin_amdgcn_sched_barrier(0);
    if (t < 10) stage(t + 2, stg);
    compute(cur, t);
    cur = cur + 1 < 3 ? cur + 1 : 0;
    stg = stg + 1 < 3 ? stg + 1 : 0;
  }
  asm volatile("s_waitcnt vmcnt(4)" ::: "memory");
  __builtin_amdgcn_s_barrier();
  __builtin_amdgcn_sched_barrier(0);
  compute(cur, 11);
}

// ---------------- pass 1: Z partials. 32 m-rows/wave ----------------
// grid = 8b x 8mt(128m) x 8nc(256n) = 512
__global__ __launch_bounds__(256, 2) void zpass_kernel(
    const bf16* __restrict__ Qb, const bf16* __restrict__ Kb, float* __restrict__ Zp)
{
  __shared__ char kbuf[2][STILE_B];    // 48 KB
  int id = blockIdx.x;
  int b = id & 7, r = id >> 3, mt = r & 7, nc = r >> 3;
  int tid = threadIdx.x, wid = tid >> 6, lane = tid & 63;
  int m0 = mt * 128 + wid * 32, n0 = nc * 256;
  int row = lane & 15, hi = lane >> 4;

  bf16x8 qf[2][12];
  #pragma unroll
  for (int s = 0; s < 2; s++) {
    const bf16* qrow = Qb + ((size_t)(b * MM + m0 + s * 16 + row)) * AA + hi * 8;
    #pragma unroll
    for (int ks = 0; ks < 12; ks++) qf[s][ks] = *reinterpret_cast<const bf16x8*>(qrow + ks * 32);
  }

  int ldso[6], srco[6];
  #pragma unroll
  for (int i = 0; i < 6; i++) {
    int off = tid * 16 + i * 4096;
    int rw = off / KROW_B, c = off - rw * KROW_B;
    ldso[i] = off;
    srco[i] = rw * KROW_B + (c ^ ((rw & 7) << 4));
  }
  const char* kgbase = (const char*)(Kb + ((size_t)(b * NN + n0)) * AA);

  int sw = (row & 7) << 4;
  int rbase = row * KROW_B;
  int x0 = rbase + ((hi * 16) ^ sw);
  int x1 = rbase + (((hi * 16) + 64) ^ sw);

  float zacc[2][NH][4];
  #pragma unroll
  for (int s = 0; s < 2; s++)
    #pragma unroll
    for (int h = 0; h < NH; h++)
      #pragma unroll
      for (int j = 0; j < 4; j++) zacc[s][h][j] = 0.f;

  auto stage = [&](int t, int buf) {
    const char* src = kgbase + (size_t)t * STILE_B;
    #pragma unroll
    for (int i = 0; i < 6; i++) ld_lds16(src + srco[i], kbuf[buf] + ldso[i]);
  };
  auto compute = [&](int buf) {
    __builtin_amdgcn_s_setprio(1);
    #pragma unroll
    for (int sub = 0; sub < 2; sub++) {
      const char* kb = kbuf[buf] + sub * TILE_B;
      #pragma unroll
      for (int h = 0; h < NH; h++) {
        bf16x8 k0 = *reinterpret_cast<const bf16x8*>(kb + h * 128 + x0);
        bf16x8 k1 = *reinterpret_cast<const bf16x8*>(kb + h * 128 + x1);
        f32x4 a0 = {0.f, 0.f, 0.f, 0.f}, a1 = {0.f, 0.f, 0.f, 0.f};
        a0 = mfma16(qf[0][2 * h], k0, a0);
        a1 = mfma16(qf[1][2 * h], k0, a1);
        a0 = mfma16(qf[0][2 * h + 1], k1, a0);
        a1 = mfma16(qf[1][2 * h + 1], k1, a1);
        #pragma unroll
        for (int j = 0; j < 4; j++) {
          zacc[0][h][j] += __builtin_amdgcn_exp2f(a0[j]);
          zacc[1][h][j] += __builtin_amdgcn_exp2f(a1[j]);
        }
      }
    }
    __builtin_amdgcn_s_setprio(0);
  };

  stage(0, 0);
  asm volatile("s_waitcnt vmcnt(0)" ::: "memory");
  __builtin_amdgcn_s_barrier();
  __builtin_amdgcn_sched_barrier(0);
  stage(1, 1);
  compute(0);

  #pragma unroll 1
  for (int i = 1; i < 8; i++) {
    asm volatile("s_waitcnt vmcnt(0)" ::: "memory");
    __builtin_amdgcn_s_barrier();
    __builtin_amdgcn_sched_barrier(0);
    if (i < 7) stage(i + 1, (i + 1) & 1);
    compute(i & 1);
  }

  #pragma unroll
  for (int s = 0; s < 2; s++)
    #pragma unroll
    for (int h = 0; h < NH; h++)
      #pragma unroll
      for (int j = 0; j < 4; j++) {
        float v = zacc[s][h][j];
        v += __shfl_xor(v, 1); v += __shfl_xor(v, 2);
        v += __shfl_xor(v, 4); v += __shfl_xor(v, 8);
        zacc[s][h][j] = v;
      }
  if (row == 0) {
    #pragma unroll
    for (int s = 0; s < 2; s++)
      #pragma unroll
      for (int h = 0; h < NH; h++)
        #pragma unroll
        for (int j = 0; j < 4; j++)
          Zp[(((size_t)nc * 8 + b) * NH + h) * MM + m0 + s * 16 + hi * 4 + j] = zacc[s][h][j];
  }
}

// ---------------- pass 2: weights W2[b][m/4][n][4] bf16; lrz folded into MFMA C-init ----------------
// grid = 512
__global__ __launch_bounds__(256, 2) void wpass_kernel(
    const bf16* __restrict__ Qb, const bf16* __restrict__ Kb,
    const float* __restrict__ Zp, bf16* __restrict__ W2)
{
  __shared__ char kbuf[2][STILE_B];    // 48 KB
  int id = blockIdx.x;
  int b = id & 7, r = id >> 3, mt = r & 7, nc = r >> 3;
  int tid = threadIdx.x, wid = tid >> 6, lane = tid & 63;
  int m0 = mt * 128 + wid * 32, n0 = nc * 256;
  int row = lane & 15, hi = lane >> 4;

  bf16x8 qf[2][12];
  #pragma unroll
  for (int s = 0; s < 2; s++) {
    const bf16* qrow = Qb + ((size_t)(b * MM + m0 + s * 16 + row)) * AA + hi * 8;
    #pragma unroll
    for (int ks = 0; ks < 12; ks++) qf[s][ks] = *reinterpret_cast<const bf16x8*>(qrow + ks * 32);
  }

  // lrz = -log2(6*Z): folded into the MFMA accumulator so w = exp2(s + lrz)
  f32x4 lrz4[2][NH];
  #pragma unroll
  for (int s = 0; s < 2; s++)
    #pragma unroll
    for (int h = 0; h < NH; h++) {
      f32x4 z = {0.f, 0.f, 0.f, 0.f};
      #pragma unroll
      for (int p = 0; p < 8; p++)
        z += *reinterpret_cast<const f32x4*>(Zp + (((size_t)p * 8 + b) * NH + h) * MM + m0 + s * 16 + hi * 4);
      f32x4 l;
      #pragma unroll
      for (int j = 0; j < 4; j++) l[j] = -__log2f(6.0f * z[j]);
      lrz4[s][h] = l;
    }

  int ldso[6], srco[6];
  #pragma unroll
  for (int i = 0; i < 6; i++) {
    int off = tid * 16 + i * 4096;
    int rw = off / KROW_B, c = off - rw * KROW_B;
    ldso[i] = off;
    srco[i] = rw * KROW_B + (c ^ ((rw & 7) << 4));
  }
  const char* kgbase = (const char*)(Kb + ((size_t)(b * NN + n0)) * AA);

  int sw = (row & 7) << 4;
  int rbase = row * KROW_B;
  int x0 = rbase + ((hi * 16) ^ sw);
  int x1 = rbase + (((hi * 16) + 64) ^ sw);

  int m4a = (m0 >> 2) + hi;
  int m4b = ((m0 + 16) >> 2) + hi;

  auto stage = [&](int t, int buf) {
    const char* src = kgbase + (size_t)t * STILE_B;
    #pragma unroll
    for (int i = 0; i < 6; i++) ld_lds16(src + srco[i], kbuf[buf] + ldso[i]);
  };
  auto compute = [&](int buf, int st) {          // issues 4 x 8B stores
    #pragma unroll
    for (int sub = 0; sub < 2; sub++) {
      const char* kb = kbuf[buf] + sub * TILE_B;
      __builtin_amdgcn_s_setprio(1);
      float w0a = 0.f, w1a = 0.f, w2a = 0.f, w3a = 0.f;
      float w0b = 0.f, w1b = 0.f, w2b = 0.f, w3b = 0.f;
      #pragma unroll
      for (int h = 0; h < NH; h++) {
        bf16x8 k0 = *reinterpret_cast<const bf16x8*>(kb + h * 128 + x0);
        bf16x8 k1 = *reinterpret_cast<const bf16x8*>(kb + h * 128 + x1);
        f32x4 a0 = mfma16(qf[0][2 * h], k0, lrz4[0][h]);
        f32x4 a1 = mfma16(qf[1][2 * h], k0, lrz4[1][h]);
        a0 = mfma16(qf[0][2 * h + 1], k1, a0);
        a1 = mfma16(qf[1][2 * h + 1], k1, a1);
        w0a += __builtin_amdgcn_exp2f(a0[0]);
        w1a += __builtin_amdgcn_exp2f(a0[1]);
        w2a += __builtin_amdgcn_exp2f(a0[2]);
        w3a += __builtin_amdgcn_exp2f(a0[3]);
        w0b += __builtin_amdgcn_exp2f(a1[0]);
        w1b += __builtin_amdgcn_exp2f(a1[1]);
        w2b += __builtin_amdgcn_exp2f(a1[2]);
        w3b += __builtin_amdgcn_exp2f(a1[3]);
      }
      __builtin_amdgcn_s_setprio(0);
      int n = n0 + (st * 2 + sub) * 16 + row;
      ushort4 qa, qb2;
      qa.x = f2bfu(w0a); qa.y = f2bfu(w1a); qa.z = f2bfu(w2a); qa.w = f2bfu(w3a);
      qb2.x = f2bfu(w0b); qb2.y = f2bfu(w1b); qb2.z = f2bfu(w2b); qb2.w = f2bfu(w3b);
      *reinterpret_cast<ushort4*>((unsigned short*)W2 + (((size_t)(b * 256 + m4a)) * NN + n) * 4) = qa;
      *reinterpret_cast<ushort4*>((unsigned short*)W2 + (((size_t)(b * 256 + m4b)) * NN + n) * 4) = qb2;
    }
  };

  stage(0, 0);
  asm volatile("s_waitcnt vmcnt(0)" ::: "memory");
  __builtin_amdgcn_s_barrier();
  __builtin_amdgcn_sched_barrier(0);
  stage(1, 1);
  compute(0, 0);

  #pragma unroll 1
  for (int i = 1; i < 8; i++) {
    // queue: [S(i-2):<=4, L(i):6, S(i-1):4] -> vmcnt(4) retires through L(i)
    asm volatile("s_waitcnt vmcnt(4)" ::: "memory");
    __builtin_amdgcn_s_barrier();
    __builtin_amdgcn_sched_barrier(0);
    if (i < 7) stage(i + 1, (i + 1) & 1);
    compute(i & 1, i);
  }
}

// ---------------- pass 3: padded-CSR gather + log. grid = 1024 ----------------
__global__ __launch_bounds__(512) void gather_kernel(
    const bf16* __restrict__ W2, const int* __restrict__ cnts,
    const int* __restrict__ idxP, float* __restrict__ out)
{
  __shared__ char wl[2 * (NN + 1) * 8];   // 32,784 B; row NN of each group = zero slot
  int id = blockIdx.x;
  int b = id & 7, mt = id >> 3;
  int g0 = mt * 2;
  int tid = threadIdx.x;

  #pragma unroll
  for (int g = 0; g < 2; g++) {
    const uint4* src = (const uint4*)((const unsigned short*)W2 + ((size_t)(b * 256 + g0 + g)) * NN * 4);
    uint4* dst = (uint4*)(wl + g * (NN + 1) * 8);
    #pragma unroll
    for (int i = tid; i < NN * 8 / 16; i += 512) dst[i] = src[i];
  }
  if (tid < 2) *reinterpret_cast<unsigned long long*>(wl + tid * (NN + 1) * 8 + NN * 8) = 0ull;
  __syncthreads();

  int c = tid;
  int cnt = cnts[b * CC + c];
  const int* ip = idxP + ((size_t)b * CC + c) * 32;
  #pragma unroll 1
  for (int g = 0; g < 2; g++) {
    const char* base = wl + g * (NN + 1) * 8;
    float s0 = 0.f, s1 = 0.f, s2 = 0.f, s3 = 0.f;
    #pragma unroll 1
    for (int i = 0; i < cnt; i += 8) {
      int4 ia = *reinterpret_cast<const int4*>(ip + i);
      int4 ib = *reinterpret_cast<const int4*>(ip + i + 4);
      ushort4 v0 = *reinterpret_cast<const ushort4*>(base + ia.x * 8);
      ushort4 v1 = *reinterpret_cast<const ushort4*>(base + ia.y * 8);
      ushort4 v2 = *reinterpret_cast<const ushort4*>(base + ia.z * 8);
      ushort4 v3 = *reinterpret_cast<const ushort4*>(base + ia.w * 8);
      ushort4 v4 = *reinterpret_cast<const ushort4*>(base + ib.x * 8);
      ushort4 v5 = *reinterpret_cast<const ushort4*>(base + ib.y * 8);
      ushort4 v6 = *reinterpret_cast<const ushort4*>(base + ib.z * 8);
      ushort4 v7 = *reinterpret_cast<const ushort4*>(base + ib.w * 8);
      s0 += bf2f(v0.x) + bf2f(v1.x) + bf2f(v2.x) + bf2f(v3.x) + bf2f(v4.x) + bf2f(v5.x) + bf2f(v6.x) + bf2f(v7.x);
      s1 += bf2f(v0.y) + bf2f(v1.y) + bf2f(v2.y) + bf2f(v3.y) + bf2f(v4.y) + bf2f(v5.y) + bf2f(v6.y) + bf2f(v7.y);
      s2 += bf2f(v0.z) + bf2f(v1.z) + bf2f(v2.z) + bf2f(v3.z) + bf2f(v4.z) + bf2f(v5.z) + bf2f(v6.z) + bf2f(v7.z);
      s3 += bf2f(v0.w) + bf2f(v1.w) + bf2f(v2.w) + bf2f(v3.w) + bf2f(v4.w) + bf2f(v5.w) + bf2f(v6.w) + bf2f(v7.w);
    }
    int m = mt * 8 + g * 4;
    out[((size_t)(m + 0) * BQ + b) * CC + c] = __logf(fmaxf(s0, 1e-5f) + 3e-5f);
    out[((size_t)(m + 1) * BQ + b) * CC + c] = __logf(fmaxf(s1, 1e-5f) + 3e-5f);
    out[((size_t)(m + 2) * BQ + b) * CC + c] = __logf(fmaxf(s2, 1e-5f) + 3e-5f);
    out[((size_t)(m + 3) * BQ + b) * CC + c] = __logf(fmaxf(s3, 1e-5f) + 3e-5f);
  }
}

extern "C" void kernel_launch(void* const* d_in, const int* in_sizes, int n_in,
                              void* d_out, int out_size, void* d_ws, size_t ws_size,
                              hipStream_t stream) {
  const float* train = (const float*)d_in[0];
  const float* test  = (const float*)d_in[1];
  const int*   tgt   = (const int*)d_in[2];
  const float* Wq    = (const float*)d_in[3];
  const float* bq    = (const float*)d_in[4];
  const float* Wk    = (const float*)d_in[5];
  const float* bk    = (const float*)d_in[6];
  float* out = (float*)d_out;

  char* ws = (char*)d_ws;
  bf16*  WqT  = (bf16*)(ws);                       //    393,216 B
  bf16*  WkT  = (bf16*)(ws + 393216);              //    393,216 B
  bf16*  Qb   = (bf16*)(ws + 786432);              //  6,291,456 B
  bf16*  Kb   = (bf16*)(ws + 7077888);             // 12,582,912 B
  float* Zp   = (float*)(ws + 19660800);           //  1,572,864 B
  bf16*  Wbuf = (bf16*)(ws + 21233664);            // 33,554,432 B
  int*   cnts = (int*)(ws + 54788096);             //     16,384 B
  int*   idxP = (int*)(ws + 54804480);             //    524,288 B  (total ~55.3 MB)

  prep_kernel<<<104, 512, 0, stream>>>(Wq, Wk, WqT, WkT, tgt, cnts, idxP);
  proj_kernel<<<768, 256, 0, stream>>>(test, train, WqT, WkT, bq, bk, Qb, Kb);
  zpass_kernel<<<512, 256, 0, stream>>>(Qb, Kb, Zp);
  wpass_kernel<<<512, 256, 0, stream>>>(Qb, Kb, Zp, Wbuf);
  gather_kernel<<<1024, 512, 0, stream>>>(Wbuf, cnts, idxP, out);
}